// Round 10
// baseline (1940.331 us; speedup 1.0000x reference)
//
#include <hip/hip_runtime.h>

#define N_NODES 100000
#define N_EDGES 3200000
#define C 50
#define PC 56          // padded channels: 7 tiles of 8
#define TC 8           // channels per tile (32 B rows)
#define NT 7           // number of tiles
#define C3 150
#define NC (N_NODES * C)
#define NCP (N_NODES * PC)
#define SCAN_BLOCKS ((N_NODES + 255) / 256)   // 391
#define GCHUNKS ((N_NODES + 3) / 4)           // 4 waves (nodes) per 256-thread block

// ---------------- CSR build ----------------

__global__ __launch_bounds__(256) void deg_kernel(const int* __restrict__ ei,
                                                  int* __restrict__ deg) {
    int e = blockIdx.x * 256 + threadIdx.x;
    if (e < N_EDGES) atomicAdd(&deg[ei[N_EDGES + e]], 1);
}

__global__ __launch_bounds__(256) void scan1_kernel(const int* __restrict__ deg,
                                                    int* __restrict__ rowptr,
                                                    int* __restrict__ blockSums) {
    __shared__ int buf[256];
    int gid = blockIdx.x * 256 + threadIdx.x;
    int v = (gid < N_NODES) ? deg[gid] : 0;
    buf[threadIdx.x] = v;
    __syncthreads();
    for (int off = 1; off < 256; off <<= 1) {
        int t = (threadIdx.x >= off) ? buf[threadIdx.x - off] : 0;
        __syncthreads();
        buf[threadIdx.x] += t;
        __syncthreads();
    }
    if (gid < N_NODES) rowptr[gid] = buf[threadIdx.x] - v;   // exclusive
    if (threadIdx.x == 255) blockSums[blockIdx.x] = buf[255];
}

__global__ __launch_bounds__(512) void scan2_kernel(int* __restrict__ blockSums) {
    __shared__ int buf[512];
    int v = (threadIdx.x < SCAN_BLOCKS) ? blockSums[threadIdx.x] : 0;
    buf[threadIdx.x] = v;
    __syncthreads();
    for (int off = 1; off < 512; off <<= 1) {
        int t = (threadIdx.x >= off) ? buf[threadIdx.x - off] : 0;
        __syncthreads();
        buf[threadIdx.x] += t;
        __syncthreads();
    }
    if (threadIdx.x < SCAN_BLOCKS) blockSums[threadIdx.x] = buf[threadIdx.x] - v;
}

__global__ __launch_bounds__(256) void scan3_kernel(int* __restrict__ rowptr,
                                                    const int* __restrict__ blockSums,
                                                    int* __restrict__ cursor) {
    int gid = blockIdx.x * 256 + threadIdx.x;
    if (gid < N_NODES) {
        int r = rowptr[gid] + blockSums[blockIdx.x];
        rowptr[gid] = r;
        cursor[gid] = r;
    }
    if (gid == 0) rowptr[N_NODES] = N_EDGES;
}

__global__ __launch_bounds__(256) void fill_kernel(const int* __restrict__ ei,
                                                   int* __restrict__ cursor,
                                                   int* __restrict__ col) {
    int e = blockIdx.x * 256 + threadIdx.x;
    if (e < N_EDGES) {
        int d = ei[N_EDGES + e];
        int pos = atomicAdd(&cursor[d], 1);
        col[pos] = ei[e];   // src
    }
}

// ---------------- per-layer kernels ----------------

// m tiled: m_t[tile][n][q] = sum_k h[n,k] * W[k, tile*8+q]  (zero for c>=50)
__global__ __launch_bounds__(256) void conv_kernel(const float* __restrict__ h, int hs,
                                                   const float* __restrict__ W,
                                                   float* __restrict__ m_t) {
    __shared__ float sW[C * C];
    for (int i = threadIdx.x; i < C * C; i += 256) sW[i] = W[i];
    __syncthreads();
    int t = blockIdx.x * 256 + threadIdx.x;
    if (t >= NCP) return;
    int n = t / PC, c = t - n * PC;
    float acc = 0.f;
    if (c < C) {
        const float* hr = h + (size_t)n * hs;
#pragma unroll
        for (int k = 0; k < C; ++k) acc = fmaf(hr[k], sW[k * C + c], acc);
    }
    int tile = c >> 3, q = c & 7;
    m_t[(size_t)tile * N_NODES * TC + (size_t)n * TC + q] = acc;
}

// tile-major gather: grid = NT * GCHUNKS blocks; per wave: (node, tile).
// 8 lanes per edge (one float each = 32 B coalesced), 8 edges in flight.
__global__ __launch_bounds__(256) void gather_kernel(const float* __restrict__ m_t,
                                                     const int* __restrict__ rowptr,
                                                     const int* __restrict__ col,
                                                     float* __restrict__ agg) {
    int tile  = blockIdx.x / GCHUNKS;
    int chunk = blockIdx.x - tile * GCHUNKS;
    int w = chunk * 4 + (threadIdx.x >> 6);          // node
    int lane = threadIdx.x & 63;
    if (w >= N_NODES) return;
    int start = rowptr[w], end = rowptr[w + 1];
    int j = lane >> 3, q = lane & 7;                 // j: edge slot, q: channel
    const float* mt = m_t + (size_t)tile * N_NODES * TC;
    float acc = 0.f;

    for (int base = start; base < end; base += 64) {
        int cidx = base + lane;
        int cols = col[cidx < N_EDGES ? cidx : (N_EDGES - 1)];  // coalesced chunk
        int cnt = end - base; if (cnt > 64) cnt = 64;
        int nt8 = (cnt + 7) >> 3;
#pragma unroll 4
        for (int t = 0; t < nt8; ++t) {
            int rel = 8 * t + j;
            int s = __shfl(cols, rel);
            float v = mt[(size_t)s * TC + q];
            acc += (rel < cnt) ? v : 0.f;
        }
    }
    // reduce the 8 edge-groups (lanes l, l^8, l^16, ..., l^56)
    acc += __shfl_xor(acc, 8);
    acc += __shfl_xor(acc, 16);
    acc += __shfl_xor(acc, 32);
    if (j == 0)
        agg[(size_t)w * PC + tile * TC + q] = acc;
}

// GRUCell: one thread per (node, out-channel); agg/hout rows padded to PC, h stride hs
__global__ __launch_bounds__(256) void gru_kernel(const float* __restrict__ agg,
                                                  const float* __restrict__ h, int hs,
                                                  const float* __restrict__ w_ih,
                                                  const float* __restrict__ w_hh,
                                                  const float* __restrict__ b_ih,
                                                  const float* __restrict__ b_hh,
                                                  float* __restrict__ hout) {
    __shared__ float s_wih[C3 * C];   // 30 KB
    __shared__ float s_whh[C3 * C];   // 30 KB
    for (int i = threadIdx.x; i < C3 * C; i += 256) {
        s_wih[i] = w_ih[i];
        s_whh[i] = w_hh[i];
    }
    __syncthreads();
    int t = blockIdx.x * 256 + threadIdx.x;
    if (t >= NC) return;
    int n = t / C, c = t - n * C;
    const float* ar = agg + (size_t)n * PC;
    const float* hr = h + (size_t)n * hs;
    float ir = 0.f, iz = 0.f, inn = 0.f, hr_ = 0.f, hz = 0.f, hn = 0.f;
#pragma unroll
    for (int k = 0; k < C; ++k) {
        float a = ar[k], hv = hr[k];
        ir  = fmaf(a,  s_wih[c * C + k],            ir);
        iz  = fmaf(a,  s_wih[(C + c) * C + k],      iz);
        inn = fmaf(a,  s_wih[(2 * C + c) * C + k],  inn);
        hr_ = fmaf(hv, s_whh[c * C + k],            hr_);
        hz  = fmaf(hv, s_whh[(C + c) * C + k],      hz);
        hn  = fmaf(hv, s_whh[(2 * C + c) * C + k],  hn);
    }
    ir  += b_ih[c];         hr_ += b_hh[c];
    iz  += b_ih[C + c];     hz  += b_hh[C + c];
    inn += b_ih[2 * C + c]; hn  += b_hh[2 * C + c];
    float r = 1.f / (1.f + expf(-(ir + hr_)));
    float z = 1.f / (1.f + expf(-(iz + hz)));
    float nn = tanhf(inn + r * hn);
    hout[(size_t)n * PC + c] = (1.f - z) * nn + z * hr[c];
}

// out[n,c] = sum_k relu(h[n,k]) * lin_w[c,k] + lin_b[c]; h padded PC, out dense C
__global__ __launch_bounds__(256) void out_kernel(const float* __restrict__ h,
                                                  const float* __restrict__ lin_w,
                                                  const float* __restrict__ lin_b,
                                                  float* __restrict__ out) {
    __shared__ float sW[C * C];
    for (int i = threadIdx.x; i < C * C; i += 256) sW[i] = lin_w[i];
    __syncthreads();
    int t = blockIdx.x * 256 + threadIdx.x;
    if (t >= NC) return;
    int n = t / C, c = t - n * C;
    const float* hr = h + (size_t)n * PC;
    float acc = lin_b[c];
#pragma unroll
    for (int k = 0; k < C; ++k) {
        float v = hr[k];
        v = v > 0.f ? v : 0.f;
        acc = fmaf(v, sW[c * C + k], acc);
    }
    out[t] = acc;
}

extern "C" void kernel_launch(void* const* d_in, const int* in_sizes, int n_in,
                              void* d_out, int out_size, void* d_ws, size_t ws_size,
                              hipStream_t stream) {
    const float* x      = (const float*)d_in[0];
    const int*   ei     = (const int*)  d_in[1];   // [2, E]
    const float* conv_w = (const float*)d_in[3];   // [3, C, C]
    const float* w_ih   = (const float*)d_in[4];
    const float* w_hh   = (const float*)d_in[5];
    const float* b_ih   = (const float*)d_in[6];
    const float* b_hh   = (const float*)d_in[7];
    const float* lin_w  = (const float*)d_in[9];
    const float* lin_b  = (const float*)d_in[10];
    float* out = (float*)d_out;

    float* ws   = (float*)d_ws;
    float* bufX = ws;                   // NCP floats (5.6M) — m tiles / h
    float* bufY = ws + NCP;             // NCP — agg (row-padded)
    float* bufZ = ws + 2 * (size_t)NCP; // NCP — h
    int* col       = (int*)(ws + 3 * (size_t)NCP);   // 3.2M
    int* rowptr    = col + N_EDGES;                  // 100001
    int* cursor    = rowptr + N_NODES + 1;           // 100001 (also deg)
    int* blockSums = cursor + N_NODES + 1;           // 391

    const int nodeBlocks  = (NC + 255) / 256;
    const int nodeBlocksP = (NCP + 255) / 256;
    const int edgeBlocks  = (N_EDGES + 255) / 256;
    const int gatherBlocks = NT * GCHUNKS;

    // ---- CSR build (deg lives in `cursor`) ----
    hipMemsetAsync(cursor, 0, (size_t)(N_NODES + 1) * sizeof(int), stream);
    deg_kernel<<<edgeBlocks, 256, 0, stream>>>(ei, cursor);
    scan1_kernel<<<SCAN_BLOCKS, 256, 0, stream>>>(cursor, rowptr, blockSums);
    scan2_kernel<<<1, 512, 0, stream>>>(blockSums);
    scan3_kernel<<<SCAN_BLOCKS, 256, 0, stream>>>(rowptr, blockSums, cursor);
    fill_kernel<<<edgeBlocks, 256, 0, stream>>>(ei, cursor, col);

    // ---- 3 layers: conv -> tiled m; tile-major gather -> agg; gru ----
    conv_kernel<<<nodeBlocksP, 256, 0, stream>>>(x, C, conv_w + 0 * C * C, bufX);
    gather_kernel<<<gatherBlocks, 256, 0, stream>>>(bufX, rowptr, col, bufY);
    gru_kernel<<<nodeBlocks, 256, 0, stream>>>(bufY, x, C, w_ih, w_hh, b_ih, b_hh, bufZ);

    conv_kernel<<<nodeBlocksP, 256, 0, stream>>>(bufZ, PC, conv_w + 1 * C * C, bufX);
    gather_kernel<<<gatherBlocks, 256, 0, stream>>>(bufX, rowptr, col, bufY);
    gru_kernel<<<nodeBlocks, 256, 0, stream>>>(bufY, bufZ, PC, w_ih, w_hh, b_ih, b_hh, bufX);

    conv_kernel<<<nodeBlocksP, 256, 0, stream>>>(bufX, PC, conv_w + 2 * C * C, bufZ);
    gather_kernel<<<gatherBlocks, 256, 0, stream>>>(bufZ, rowptr, col, bufY);
    gru_kernel<<<nodeBlocks, 256, 0, stream>>>(bufY, bufX, PC, w_ih, w_hh, b_ih, b_hh, bufZ);

    out_kernel<<<nodeBlocks, 256, 0, stream>>>(bufZ, lin_w, lin_b, out);
}

// Round 11
// 1384.706 us; speedup vs baseline: 1.4013x; 1.4013x over previous
//
#include <hip/hip_runtime.h>
#include <hip/hip_fp16.h>

#define N_NODES 100000
#define N_EDGES 3200000
#define C 50
#define PC 56          // padded fp32 row for h/agg (224 B)
#define PH 64          // padded fp16 row for m (128 B = 2 cache lines)
#define C3 150
#define NC (N_NODES * C)
#define NCP (N_NODES * PC)
#define SCAN_BLOCKS ((N_NODES + 255) / 256)   // 391

// ---------------- CSR build ----------------

__global__ __launch_bounds__(256) void deg_kernel(const int* __restrict__ ei,
                                                  int* __restrict__ deg) {
    int e = blockIdx.x * 256 + threadIdx.x;
    if (e < N_EDGES) atomicAdd(&deg[ei[N_EDGES + e]], 1);
}

__global__ __launch_bounds__(256) void scan1_kernel(const int* __restrict__ deg,
                                                    int* __restrict__ rowptr,
                                                    int* __restrict__ blockSums) {
    __shared__ int buf[256];
    int gid = blockIdx.x * 256 + threadIdx.x;
    int v = (gid < N_NODES) ? deg[gid] : 0;
    buf[threadIdx.x] = v;
    __syncthreads();
    for (int off = 1; off < 256; off <<= 1) {
        int t = (threadIdx.x >= off) ? buf[threadIdx.x - off] : 0;
        __syncthreads();
        buf[threadIdx.x] += t;
        __syncthreads();
    }
    if (gid < N_NODES) rowptr[gid] = buf[threadIdx.x] - v;   // exclusive
    if (threadIdx.x == 255) blockSums[blockIdx.x] = buf[255];
}

__global__ __launch_bounds__(512) void scan2_kernel(int* __restrict__ blockSums) {
    __shared__ int buf[512];
    int v = (threadIdx.x < SCAN_BLOCKS) ? blockSums[threadIdx.x] : 0;
    buf[threadIdx.x] = v;
    __syncthreads();
    for (int off = 1; off < 512; off <<= 1) {
        int t = (threadIdx.x >= off) ? buf[threadIdx.x - off] : 0;
        __syncthreads();
        buf[threadIdx.x] += t;
        __syncthreads();
    }
    if (threadIdx.x < SCAN_BLOCKS) blockSums[threadIdx.x] = buf[threadIdx.x] - v;
}

__global__ __launch_bounds__(256) void scan3_kernel(int* __restrict__ rowptr,
                                                    const int* __restrict__ blockSums,
                                                    int* __restrict__ cursor) {
    int gid = blockIdx.x * 256 + threadIdx.x;
    if (gid < N_NODES) {
        int r = rowptr[gid] + blockSums[blockIdx.x];
        rowptr[gid] = r;
        cursor[gid] = r;
    }
    if (gid == 0) rowptr[N_NODES] = N_EDGES;
}

__global__ __launch_bounds__(256) void fill_kernel(const int* __restrict__ ei,
                                                   int* __restrict__ cursor,
                                                   int* __restrict__ col) {
    int e = blockIdx.x * 256 + threadIdx.x;
    if (e < N_EDGES) {
        int d = ei[N_EDGES + e];
        int pos = atomicAdd(&cursor[d], 1);
        col[pos] = ei[e];   // src
    }
}

// ---------------- per-layer kernels ----------------

// m_h[n, c<50] = (half) sum_k h[n,k] * W[k,c]; channels 50..55 zero; 56..63 never read
__global__ __launch_bounds__(256) void conv_kernel(const float* __restrict__ h, int hs,
                                                   const float* __restrict__ W,
                                                   __half* __restrict__ m_h) {
    __shared__ float sW[C * C];
    for (int i = threadIdx.x; i < C * C; i += 256) sW[i] = W[i];
    __syncthreads();
    int t = blockIdx.x * 256 + threadIdx.x;
    if (t >= NCP) return;
    int n = t / PC, c = t - n * PC;
    float acc = 0.f;
    if (c < C) {
        const float* hr = h + (size_t)n * hs;
#pragma unroll
        for (int k = 0; k < C; ++k) acc = fmaf(hr[k], sW[k * C + c], acc);
    }
    m_h[(size_t)n * PH + c] = __float2half(acc);
}

// wave-per-node gather over fp16 rows: 8 lanes/edge (uint4 = 16 B each -> 128 B row),
// 8 edges in flight; fp32 accumulate; cross-slot shfl_xor reduce; fp32 agg out.
__global__ __launch_bounds__(256) void gather_kernel(const __half* __restrict__ m_h,
                                                     const int* __restrict__ rowptr,
                                                     const int* __restrict__ col,
                                                     float* __restrict__ agg) {
    int w = (blockIdx.x * 256 + threadIdx.x) >> 6;   // node (wave-uniform)
    int lane = threadIdx.x & 63;
    if (w >= N_NODES) return;
    int start = rowptr[w], end = rowptr[w + 1];
    int j = lane >> 3, q = lane & 7;                 // j: edge slot, q: 8-half chunk
    bool qok = (q < 7);                              // 7 chunks * 8 halves = 56 ch
    int hoff = qok ? (q * 8) : 48;                   // halves; q>=7 reads safe dup
    float acc0 = 0.f, acc1 = 0.f, acc2 = 0.f, acc3 = 0.f;
    float acc4 = 0.f, acc5 = 0.f, acc6 = 0.f, acc7 = 0.f;

    for (int base = start; base < end; base += 64) {
        int cidx = base + lane;
        int cols = col[cidx < N_EDGES ? cidx : (N_EDGES - 1)];  // coalesced chunk
        int cnt = end - base; if (cnt > 64) cnt = 64;
        int nt8 = (cnt + 7) >> 3;
#pragma unroll 4
        for (int t = 0; t < nt8; ++t) {
            int rel = 8 * t + j;
            int s = __shfl(cols, rel);
            bool valid = qok && (rel < cnt);
            const uint4 v = *reinterpret_cast<const uint4*>(m_h + (size_t)s * PH + hoff);
            float2 f0 = __half22float2(*reinterpret_cast<const __half2*>(&v.x));
            float2 f1 = __half22float2(*reinterpret_cast<const __half2*>(&v.y));
            float2 f2 = __half22float2(*reinterpret_cast<const __half2*>(&v.z));
            float2 f3 = __half22float2(*reinterpret_cast<const __half2*>(&v.w));
            acc0 += valid ? f0.x : 0.f;  acc1 += valid ? f0.y : 0.f;
            acc2 += valid ? f1.x : 0.f;  acc3 += valid ? f1.y : 0.f;
            acc4 += valid ? f2.x : 0.f;  acc5 += valid ? f2.y : 0.f;
            acc6 += valid ? f3.x : 0.f;  acc7 += valid ? f3.y : 0.f;
        }
    }
    // reduce across the 8 edge slots (lanes l, l^8, ..., l^56)
#pragma unroll
    for (int s = 8; s <= 32; s <<= 1) {
        acc0 += __shfl_xor(acc0, s); acc1 += __shfl_xor(acc1, s);
        acc2 += __shfl_xor(acc2, s); acc3 += __shfl_xor(acc3, s);
        acc4 += __shfl_xor(acc4, s); acc5 += __shfl_xor(acc5, s);
        acc6 += __shfl_xor(acc6, s); acc7 += __shfl_xor(acc7, s);
    }
    if (j == 0 && qok) {
        float* ar = agg + (size_t)w * PC + q * 8;
        *reinterpret_cast<float4*>(ar)     = make_float4(acc0, acc1, acc2, acc3);
        *reinterpret_cast<float4*>(ar + 4) = make_float4(acc4, acc5, acc6, acc7);
    }
}

// GRUCell: one thread per (node, out-channel); agg/hout rows padded to PC, h stride hs
__global__ __launch_bounds__(256) void gru_kernel(const float* __restrict__ agg,
                                                  const float* __restrict__ h, int hs,
                                                  const float* __restrict__ w_ih,
                                                  const float* __restrict__ w_hh,
                                                  const float* __restrict__ b_ih,
                                                  const float* __restrict__ b_hh,
                                                  float* __restrict__ hout) {
    __shared__ float s_wih[C3 * C];   // 30 KB
    __shared__ float s_whh[C3 * C];   // 30 KB
    for (int i = threadIdx.x; i < C3 * C; i += 256) {
        s_wih[i] = w_ih[i];
        s_whh[i] = w_hh[i];
    }
    __syncthreads();
    int t = blockIdx.x * 256 + threadIdx.x;
    if (t >= NC) return;
    int n = t / C, c = t - n * C;
    const float* ar = agg + (size_t)n * PC;
    const float* hr = h + (size_t)n * hs;
    float ir = 0.f, iz = 0.f, inn = 0.f, hr_ = 0.f, hz = 0.f, hn = 0.f;
#pragma unroll
    for (int k = 0; k < C; ++k) {
        float a = ar[k], hv = hr[k];
        ir  = fmaf(a,  s_wih[c * C + k],            ir);
        iz  = fmaf(a,  s_wih[(C + c) * C + k],      iz);
        inn = fmaf(a,  s_wih[(2 * C + c) * C + k],  inn);
        hr_ = fmaf(hv, s_whh[c * C + k],            hr_);
        hz  = fmaf(hv, s_whh[(C + c) * C + k],      hz);
        hn  = fmaf(hv, s_whh[(2 * C + c) * C + k],  hn);
    }
    ir  += b_ih[c];         hr_ += b_hh[c];
    iz  += b_ih[C + c];     hz  += b_hh[C + c];
    inn += b_ih[2 * C + c]; hn  += b_hh[2 * C + c];
    float r = 1.f / (1.f + expf(-(ir + hr_)));
    float z = 1.f / (1.f + expf(-(iz + hz)));
    float nn = tanhf(inn + r * hn);
    hout[(size_t)n * PC + c] = (1.f - z) * nn + z * hr[c];
}

// out[n,c] = sum_k relu(h[n,k]) * lin_w[c,k] + lin_b[c]; h padded PC, out dense C
__global__ __launch_bounds__(256) void out_kernel(const float* __restrict__ h,
                                                  const float* __restrict__ lin_w,
                                                  const float* __restrict__ lin_b,
                                                  float* __restrict__ out) {
    __shared__ float sW[C * C];
    for (int i = threadIdx.x; i < C * C; i += 256) sW[i] = lin_w[i];
    __syncthreads();
    int t = blockIdx.x * 256 + threadIdx.x;
    if (t >= NC) return;
    int n = t / C, c = t - n * C;
    const float* hr = h + (size_t)n * PC;
    float acc = lin_b[c];
#pragma unroll
    for (int k = 0; k < C; ++k) {
        float v = hr[k];
        v = v > 0.f ? v : 0.f;
        acc = fmaf(v, sW[c * C + k], acc);
    }
    out[t] = acc;
}

extern "C" void kernel_launch(void* const* d_in, const int* in_sizes, int n_in,
                              void* d_out, int out_size, void* d_ws, size_t ws_size,
                              hipStream_t stream) {
    const float* x      = (const float*)d_in[0];
    const int*   ei     = (const int*)  d_in[1];   // [2, E]
    const float* conv_w = (const float*)d_in[3];   // [3, C, C]
    const float* w_ih   = (const float*)d_in[4];
    const float* w_hh   = (const float*)d_in[5];
    const float* b_ih   = (const float*)d_in[6];
    const float* b_hh   = (const float*)d_in[7];
    const float* lin_w  = (const float*)d_in[9];
    const float* lin_b  = (const float*)d_in[10];
    float* out = (float*)d_out;

    float* ws   = (float*)d_ws;
    float* h1   = ws;                   // NCP floats
    float* h2   = ws + NCP;             // NCP
    float* agg  = ws + 2 * (size_t)NCP; // NCP
    __half* m_h = (__half*)(ws + 3 * (size_t)NCP);        // N_NODES*PH halves = 3.2M floats
    int* col       = (int*)(ws + 3 * (size_t)NCP + (size_t)N_NODES * PH / 2);  // 3.2M ints
    int* rowptr    = col + N_EDGES;                  // 100001
    int* cursor    = rowptr + N_NODES + 1;           // 100001 (also deg)
    int* blockSums = cursor + N_NODES + 1;           // 391

    const int nodeBlocks  = (NC + 255) / 256;
    const int nodeBlocksP = (NCP + 255) / 256;
    const int edgeBlocks  = (N_EDGES + 255) / 256;
    const int waveBlocks  = (N_NODES * 64 + 255) / 256;

    // ---- CSR build (deg lives in `cursor`) ----
    hipMemsetAsync(cursor, 0, (size_t)(N_NODES + 1) * sizeof(int), stream);
    deg_kernel<<<edgeBlocks, 256, 0, stream>>>(ei, cursor);
    scan1_kernel<<<SCAN_BLOCKS, 256, 0, stream>>>(cursor, rowptr, blockSums);
    scan2_kernel<<<1, 512, 0, stream>>>(blockSums);
    scan3_kernel<<<SCAN_BLOCKS, 256, 0, stream>>>(rowptr, blockSums, cursor);
    fill_kernel<<<edgeBlocks, 256, 0, stream>>>(ei, cursor, col);

    // ---- 3 layers: conv -> fp16 m; gather -> fp32 agg; gru ----
    conv_kernel<<<nodeBlocksP, 256, 0, stream>>>(x, C, conv_w + 0 * C * C, m_h);
    gather_kernel<<<waveBlocks, 256, 0, stream>>>(m_h, rowptr, col, agg);
    gru_kernel<<<nodeBlocks, 256, 0, stream>>>(agg, x, C, w_ih, w_hh, b_ih, b_hh, h1);

    conv_kernel<<<nodeBlocksP, 256, 0, stream>>>(h1, PC, conv_w + 1 * C * C, m_h);
    gather_kernel<<<waveBlocks, 256, 0, stream>>>(m_h, rowptr, col, agg);
    gru_kernel<<<nodeBlocks, 256, 0, stream>>>(agg, h1, PC, w_ih, w_hh, b_ih, b_hh, h2);

    conv_kernel<<<nodeBlocksP, 256, 0, stream>>>(h2, PC, conv_w + 2 * C * C, m_h);
    gather_kernel<<<waveBlocks, 256, 0, stream>>>(m_h, rowptr, col, agg);
    gru_kernel<<<nodeBlocks, 256, 0, stream>>>(agg, h2, PC, w_ih, w_hh, b_ih, b_hh, h1);

    out_kernel<<<nodeBlocks, 256, 0, stream>>>(h1, lin_w, lin_b, out);
}

// Round 12
// 807.335 us; speedup vs baseline: 2.4034x; 1.7152x over previous
//
#include <hip/hip_runtime.h>
#include <hip/hip_fp16.h>

#define N_NODES 100000
#define N_EDGES 3200000
#define C 50
#define PC 56          // padded fp32 row for h/agg (224 B)
#define PH 64          // padded fp16 row for m (128 B)
#define C3 150
#define NC (N_NODES * C)
#define NCP (N_NODES * PC)
#define SCAN_BLOCKS ((N_NODES + 255) / 256)   // 391
#define NTILES (N_NODES / 16)                 // 6250 (exact)

typedef _Float16 half8 __attribute__((ext_vector_type(8)));
typedef float floatx4 __attribute__((ext_vector_type(4)));

// ---------------- CSR build (unchanged) ----------------

__global__ __launch_bounds__(256) void deg_kernel(const int* __restrict__ ei,
                                                  int* __restrict__ deg) {
    int e = blockIdx.x * 256 + threadIdx.x;
    if (e < N_EDGES) atomicAdd(&deg[ei[N_EDGES + e]], 1);
}

__global__ __launch_bounds__(256) void scan1_kernel(const int* __restrict__ deg,
                                                    int* __restrict__ rowptr,
                                                    int* __restrict__ blockSums) {
    __shared__ int buf[256];
    int gid = blockIdx.x * 256 + threadIdx.x;
    int v = (gid < N_NODES) ? deg[gid] : 0;
    buf[threadIdx.x] = v;
    __syncthreads();
    for (int off = 1; off < 256; off <<= 1) {
        int t = (threadIdx.x >= off) ? buf[threadIdx.x - off] : 0;
        __syncthreads();
        buf[threadIdx.x] += t;
        __syncthreads();
    }
    if (gid < N_NODES) rowptr[gid] = buf[threadIdx.x] - v;   // exclusive
    if (threadIdx.x == 255) blockSums[blockIdx.x] = buf[255];
}

__global__ __launch_bounds__(512) void scan2_kernel(int* __restrict__ blockSums) {
    __shared__ int buf[512];
    int v = (threadIdx.x < SCAN_BLOCKS) ? blockSums[threadIdx.x] : 0;
    buf[threadIdx.x] = v;
    __syncthreads();
    for (int off = 1; off < 512; off <<= 1) {
        int t = (threadIdx.x >= off) ? buf[threadIdx.x - off] : 0;
        __syncthreads();
        buf[threadIdx.x] += t;
        __syncthreads();
    }
    if (threadIdx.x < SCAN_BLOCKS) blockSums[threadIdx.x] = buf[threadIdx.x] - v;
}

__global__ __launch_bounds__(256) void scan3_kernel(int* __restrict__ rowptr,
                                                    const int* __restrict__ blockSums,
                                                    int* __restrict__ cursor) {
    int gid = blockIdx.x * 256 + threadIdx.x;
    if (gid < N_NODES) {
        int r = rowptr[gid] + blockSums[blockIdx.x];
        rowptr[gid] = r;
        cursor[gid] = r;
    }
    if (gid == 0) rowptr[N_NODES] = N_EDGES;
}

__global__ __launch_bounds__(256) void fill_kernel(const int* __restrict__ ei,
                                                   int* __restrict__ cursor,
                                                   int* __restrict__ col) {
    int e = blockIdx.x * 256 + threadIdx.x;
    if (e < N_EDGES) {
        int d = ei[N_EDGES + e];
        int pos = atomicAdd(&cursor[d], 1);
        col[pos] = ei[e];   // src
    }
}

// ---------------- weight prep: fp16, [n][64 k] rows, zero-padded ----------------
// layout (4096-half matrices): [0..2]=conv L0..L2, [3..5]=ih gates r,z,n,
// [6..8]=hh gates, [9]=out
__global__ __launch_bounds__(256) void prep_kernel(const float* __restrict__ conv_w,
                                                   const float* __restrict__ w_ih,
                                                   const float* __restrict__ w_hh,
                                                   const float* __restrict__ lin_w,
                                                   _Float16* __restrict__ wb) {
    int t = blockIdx.x * 256 + threadIdx.x;
    if (t >= 10 * 4096) return;
    int mat = t >> 12, idx = t & 4095, n = idx >> 6, k = idx & 63;
    float v = 0.f;
    if (n < C && k < C) {
        if (mat < 3)      v = conv_w[mat * C * C + k * C + n];        // W[k][c=n]
        else if (mat < 6) v = w_ih[((mat - 3) * C + n) * C + k];
        else if (mat < 9) v = w_hh[((mat - 6) * C + n) * C + k];
        else              v = lin_w[n * C + k];
    }
    wb[t] = (_Float16)v;
}

// x [N][50] -> h0 [N][56] zero-padded
__global__ __launch_bounds__(256) void pad_x_kernel(const float* __restrict__ x,
                                                    float* __restrict__ h0) {
    int t = blockIdx.x * 256 + threadIdx.x;
    if (t >= NCP) return;
    int n = t / PC, c = t - n * PC;
    h0[t] = (c < C) ? x[n * C + c] : 0.f;
}

// ---------------- MFMA fragment loaders ----------------
// A (16x32 f16): lane: row = base+(l&15), k = ks*32 + (l>>4)*8 + j
__device__ inline half8 load_a_frag(const float* __restrict__ base, int row, int ks,
                                    int lane, bool relu) {
    int kb = ks * 32 + ((lane >> 4) << 3);
    half8 r;
    if (kb >= PC) {
#pragma unroll
        for (int j = 0; j < 8; ++j) r[j] = (_Float16)0.f;
        return r;
    }
    const float* p = base + (size_t)row * PC + kb;
#pragma unroll
    for (int j = 0; j < 8; ++j) {
        float v = p[j];
        if (relu) v = v > 0.f ? v : 0.f;
        r[j] = (_Float16)v;
    }
    return r;
}

// B (32x16 f16): lane: n = nt*16+(l&15), k = ks*32 + (l>>4)*8 + j  (wb row-major [n][64])
__device__ inline half8 load_b_frag(const _Float16* __restrict__ wb, int nt, int ks, int lane) {
    const _Float16* p = wb + (((nt << 4) + (lane & 15)) << 6) + (ks << 5) + ((lane >> 4) << 3);
    return *(const half8*)p;
}

__device__ inline float sigmoidf_(float x) { return 1.f / (1.f + __expf(-x)); }
__device__ inline float tanhf_(float x)    { return 2.f * sigmoidf_(2.f * x) - 1.f; }

// ---------------- dense kernels via MFMA ----------------

// m_h[n][64] (fp16) = h @ W ; wave per 16-node tile
__global__ __launch_bounds__(256) void gemm_conv(const float* __restrict__ h,
                                                 const _Float16* __restrict__ wb,
                                                 _Float16* __restrict__ m_h) {
    int wid = threadIdx.x >> 6, lane = threadIdx.x & 63;
    int tile = blockIdx.x * 4 + wid;
    if (tile >= NTILES) return;
    int base = tile * 16;
    int arow = base + (lane & 15);
    half8 a0 = load_a_frag(h, arow, 0, lane, false);
    half8 a1 = load_a_frag(h, arow, 1, lane, false);
#pragma unroll
    for (int nt = 0; nt < 4; ++nt) {
        floatx4 acc = {0.f, 0.f, 0.f, 0.f};
        acc = __builtin_amdgcn_mfma_f32_16x16x32_f16(a0, load_b_frag(wb, nt, 0, lane), acc, 0, 0, 0);
        acc = __builtin_amdgcn_mfma_f32_16x16x32_f16(a1, load_b_frag(wb, nt, 1, lane), acc, 0, 0, 0);
        int col = (nt << 4) + (lane & 15);
#pragma unroll
        for (int e = 0; e < 4; ++e) {
            int row = base + ((lane >> 4) << 2) + e;
            m_h[(size_t)row * PH + col] = (_Float16)acc[e];
        }
    }
}

// fused GRU: gi = agg@W_ih^T + b_ih; gh = hin@W_hh^T + b_hh; gate math; hout padded
__global__ __launch_bounds__(256) void gemm_gru(const float* __restrict__ agg,
                                                const float* __restrict__ hin,
                                                const _Float16* __restrict__ wb_ih,
                                                const _Float16* __restrict__ wb_hh,
                                                const float* __restrict__ b_ih,
                                                const float* __restrict__ b_hh,
                                                float* __restrict__ hout) {
    int wid = threadIdx.x >> 6, lane = threadIdx.x & 63;
    int tile = blockIdx.x * 4 + wid;
    if (tile >= NTILES) return;
    int base = tile * 16;
    int arow = base + (lane & 15);
    half8 aA[2], aH[2];
#pragma unroll
    for (int ks = 0; ks < 2; ++ks) {
        aA[ks] = load_a_frag(agg, arow, ks, lane, false);
        aH[ks] = load_a_frag(hin, arow, ks, lane, false);
    }
    float r_[4][4], z_[4][4];
#pragma unroll
    for (int g = 0; g < 3; ++g) {
        const _Float16* wih = wb_ih + g * 4096;
        const _Float16* whh = wb_hh + g * 4096;
#pragma unroll
        for (int nt = 0; nt < 4; ++nt) {
            floatx4 accI = {0.f, 0.f, 0.f, 0.f};
            floatx4 accH = {0.f, 0.f, 0.f, 0.f};
#pragma unroll
            for (int ks = 0; ks < 2; ++ks) {
                accI = __builtin_amdgcn_mfma_f32_16x16x32_f16(aA[ks], load_b_frag(wih, nt, ks, lane), accI, 0, 0, 0);
                accH = __builtin_amdgcn_mfma_f32_16x16x32_f16(aH[ks], load_b_frag(whh, nt, ks, lane), accH, 0, 0, 0);
            }
            int col = (nt << 4) + (lane & 15);
            float bi = (col < C) ? b_ih[g * C + col] : 0.f;
            float bh = (col < C) ? b_hh[g * C + col] : 0.f;
            if (g == 0) {
#pragma unroll
                for (int e = 0; e < 4; ++e) r_[nt][e] = sigmoidf_((accI[e] + bi) + (accH[e] + bh));
            } else if (g == 1) {
#pragma unroll
                for (int e = 0; e < 4; ++e) z_[nt][e] = sigmoidf_((accI[e] + bi) + (accH[e] + bh));
            } else {
#pragma unroll
                for (int e = 0; e < 4; ++e) {
                    int row = base + ((lane >> 4) << 2) + e;
                    if (col < C) {
                        float hv = hin[(size_t)row * PC + col];
                        float nn = tanhf_((accI[e] + bi) + r_[nt][e] * (accH[e] + bh));
                        float z = z_[nt][e];
                        hout[(size_t)row * PC + col] = (1.f - z) * nn + z * hv;
                    } else if (col < PC) {
                        hout[(size_t)row * PC + col] = 0.f;
                    }
                }
            }
        }
    }
}

// out[n][50] = relu(h) @ lin_w^T + lin_b
__global__ __launch_bounds__(256) void gemm_out(const float* __restrict__ h,
                                                const _Float16* __restrict__ wb,
                                                const float* __restrict__ lin_b,
                                                float* __restrict__ out) {
    int wid = threadIdx.x >> 6, lane = threadIdx.x & 63;
    int tile = blockIdx.x * 4 + wid;
    if (tile >= NTILES) return;
    int base = tile * 16;
    int arow = base + (lane & 15);
    half8 a0 = load_a_frag(h, arow, 0, lane, true);
    half8 a1 = load_a_frag(h, arow, 1, lane, true);
#pragma unroll
    for (int nt = 0; nt < 4; ++nt) {
        floatx4 acc = {0.f, 0.f, 0.f, 0.f};
        acc = __builtin_amdgcn_mfma_f32_16x16x32_f16(a0, load_b_frag(wb, nt, 0, lane), acc, 0, 0, 0);
        acc = __builtin_amdgcn_mfma_f32_16x16x32_f16(a1, load_b_frag(wb, nt, 1, lane), acc, 0, 0, 0);
        int col = (nt << 4) + (lane & 15);
        if (col < C) {
            float b = lin_b[col];
#pragma unroll
            for (int e = 0; e < 4; ++e) {
                int row = base + ((lane >> 4) << 2) + e;
                out[(size_t)row * C + col] = acc[e] + b;
            }
        }
    }
}

// ---------------- gather (unchanged from R11) ----------------
__global__ __launch_bounds__(256) void gather_kernel(const __half* __restrict__ m_h,
                                                     const int* __restrict__ rowptr,
                                                     const int* __restrict__ col,
                                                     float* __restrict__ agg) {
    int w = (blockIdx.x * 256 + threadIdx.x) >> 6;   // node (wave-uniform)
    int lane = threadIdx.x & 63;
    if (w >= N_NODES) return;
    int start = rowptr[w], end = rowptr[w + 1];
    int j = lane >> 3, q = lane & 7;
    bool qok = (q < 7);
    int hoff = qok ? (q * 8) : 48;
    float acc0 = 0.f, acc1 = 0.f, acc2 = 0.f, acc3 = 0.f;
    float acc4 = 0.f, acc5 = 0.f, acc6 = 0.f, acc7 = 0.f;

    for (int base = start; base < end; base += 64) {
        int cidx = base + lane;
        int cols = col[cidx < N_EDGES ? cidx : (N_EDGES - 1)];
        int cnt = end - base; if (cnt > 64) cnt = 64;
        int nt8 = (cnt + 7) >> 3;
#pragma unroll 4
        for (int t = 0; t < nt8; ++t) {
            int rel = 8 * t + j;
            int s = __shfl(cols, rel);
            bool valid = qok && (rel < cnt);
            const uint4 v = *reinterpret_cast<const uint4*>(m_h + (size_t)s * PH + hoff);
            float2 f0 = __half22float2(*reinterpret_cast<const __half2*>(&v.x));
            float2 f1 = __half22float2(*reinterpret_cast<const __half2*>(&v.y));
            float2 f2 = __half22float2(*reinterpret_cast<const __half2*>(&v.z));
            float2 f3 = __half22float2(*reinterpret_cast<const __half2*>(&v.w));
            acc0 += valid ? f0.x : 0.f;  acc1 += valid ? f0.y : 0.f;
            acc2 += valid ? f1.x : 0.f;  acc3 += valid ? f1.y : 0.f;
            acc4 += valid ? f2.x : 0.f;  acc5 += valid ? f2.y : 0.f;
            acc6 += valid ? f3.x : 0.f;  acc7 += valid ? f3.y : 0.f;
        }
    }
#pragma unroll
    for (int s = 8; s <= 32; s <<= 1) {
        acc0 += __shfl_xor(acc0, s); acc1 += __shfl_xor(acc1, s);
        acc2 += __shfl_xor(acc2, s); acc3 += __shfl_xor(acc3, s);
        acc4 += __shfl_xor(acc4, s); acc5 += __shfl_xor(acc5, s);
        acc6 += __shfl_xor(acc6, s); acc7 += __shfl_xor(acc7, s);
    }
    if (j == 0 && qok) {
        float* ar = agg + (size_t)w * PC + q * 8;
        *reinterpret_cast<float4*>(ar)     = make_float4(acc0, acc1, acc2, acc3);
        *reinterpret_cast<float4*>(ar + 4) = make_float4(acc4, acc5, acc6, acc7);
    }
}

extern "C" void kernel_launch(void* const* d_in, const int* in_sizes, int n_in,
                              void* d_out, int out_size, void* d_ws, size_t ws_size,
                              hipStream_t stream) {
    const float* x      = (const float*)d_in[0];
    const int*   ei     = (const int*)  d_in[1];
    const float* conv_w = (const float*)d_in[3];
    const float* w_ih   = (const float*)d_in[4];
    const float* w_hh   = (const float*)d_in[5];
    const float* b_ih   = (const float*)d_in[6];
    const float* b_hh   = (const float*)d_in[7];
    const float* lin_w  = (const float*)d_in[9];
    const float* lin_b  = (const float*)d_in[10];
    float* out = (float*)d_out;

    float* ws  = (float*)d_ws;
    float* h0  = ws;                    // NCP floats
    float* h1  = ws + NCP;              // NCP
    float* agg = ws + 2 * (size_t)NCP;  // NCP
    _Float16* m_h = (_Float16*)(ws + 3 * (size_t)NCP);        // N*64 halves
    _Float16* wb  = m_h + (size_t)N_NODES * PH;               // 40960 halves
    int* col       = (int*)(wb + 10 * 4096);
    int* rowptr    = col + N_EDGES;
    int* cursor    = rowptr + N_NODES + 1;
    int* blockSums = cursor + N_NODES + 1;

    const int nodeBlocksP = (NCP + 255) / 256;
    const int edgeBlocks  = (N_EDGES + 255) / 256;
    const int waveBlocks  = (N_NODES * 64 + 255) / 256;
    const int gemmBlocks  = (NTILES + 3) / 4;   // 1563

    // prep + pad
    prep_kernel<<<160, 256, 0, stream>>>(conv_w, w_ih, w_hh, lin_w, wb);
    pad_x_kernel<<<nodeBlocksP, 256, 0, stream>>>(x, h0);

    // CSR build
    hipMemsetAsync(cursor, 0, (size_t)(N_NODES + 1) * sizeof(int), stream);
    deg_kernel<<<edgeBlocks, 256, 0, stream>>>(ei, cursor);
    scan1_kernel<<<SCAN_BLOCKS, 256, 0, stream>>>(cursor, rowptr, blockSums);
    scan2_kernel<<<1, 512, 0, stream>>>(blockSums);
    scan3_kernel<<<SCAN_BLOCKS, 256, 0, stream>>>(rowptr, blockSums, cursor);
    fill_kernel<<<edgeBlocks, 256, 0, stream>>>(ei, cursor, col);

    // 3 layers
    gemm_conv<<<gemmBlocks, 256, 0, stream>>>(h0, wb + 0 * 4096, m_h);
    gather_kernel<<<waveBlocks, 256, 0, stream>>>((const __half*)m_h, rowptr, col, agg);
    gemm_gru<<<gemmBlocks, 256, 0, stream>>>(agg, h0, wb + 3 * 4096, wb + 6 * 4096, b_ih, b_hh, h1);

    gemm_conv<<<gemmBlocks, 256, 0, stream>>>(h1, wb + 1 * 4096, m_h);
    gather_kernel<<<waveBlocks, 256, 0, stream>>>((const __half*)m_h, rowptr, col, agg);
    gemm_gru<<<gemmBlocks, 256, 0, stream>>>(agg, h1, wb + 3 * 4096, wb + 6 * 4096, b_ih, b_hh, h0);

    gemm_conv<<<gemmBlocks, 256, 0, stream>>>(h0, wb + 2 * 4096, m_h);
    gather_kernel<<<waveBlocks, 256, 0, stream>>>((const __half*)m_h, rowptr, col, agg);
    gemm_gru<<<gemmBlocks, 256, 0, stream>>>(agg, h0, wb + 3 * 4096, wb + 6 * 4096, b_ih, b_hh, h1);

    gemm_out<<<gemmBlocks, 256, 0, stream>>>(h1, wb + 9 * 4096, lin_b, out);
}

// Round 14
// 515.701 us; speedup vs baseline: 3.7625x; 1.5655x over previous
//
#include <hip/hip_runtime.h>
#include <hip/hip_fp16.h>

#define N_NODES 100000
#define N_EDGES 3200000
#define C 50
#define PC 56          // padded fp32 row for h/agg (224 B)
#define PH 64          // padded fp16 row for m (128 B)
#define NC (N_NODES * C)
#define NCP (N_NODES * PC)
#define NTILES (N_NODES / 16)                 // 6250
#define NBUK ((N_NODES + 127) / 128)          // 782 buckets of 128 nodes
#define EPB 4096                              // edges per block (bucket passes)
#define EB  ((N_EDGES + EPB - 1) / EPB)       // 782
#define EPT (EPB / 256)                       // 16 edges per thread

typedef _Float16 half8 __attribute__((ext_vector_type(8)));
typedef float floatx4 __attribute__((ext_vector_type(4)));

// ---------------- bucket-sorted CSR build ----------------

// pass 1: per-block LDS histogram of dst-buckets -> global bucketCnt
__global__ __launch_bounds__(256) void bhist_kernel(const int* __restrict__ ei,
                                                    int* __restrict__ bucketCnt) {
    __shared__ int hist[NBUK];
    for (int t = threadIdx.x; t < NBUK; t += 256) hist[t] = 0;
    __syncthreads();
    int e0 = blockIdx.x * EPB;
#pragma unroll
    for (int i = 0; i < EPT; ++i) {
        int e = e0 + i * 256 + threadIdx.x;
        if (e < N_EDGES) atomicAdd(&hist[ei[N_EDGES + e] >> 7], 1);
    }
    __syncthreads();
    for (int t = threadIdx.x; t < NBUK; t += 256)
        if (hist[t]) atomicAdd(&bucketCnt[t], hist[t]);
}

// pass 2: exclusive scan of bucketCnt (782) -> bucketOff[0..NBUK], init bucketCursor
__global__ __launch_bounds__(1024) void bscan_kernel(const int* __restrict__ bucketCnt,
                                                     int* __restrict__ bucketOff,
                                                     int* __restrict__ bucketCursor) {
    __shared__ int buf[1024];
    int t = threadIdx.x;
    int v = (t < NBUK) ? bucketCnt[t] : 0;
    buf[t] = v;
    __syncthreads();
    for (int off = 1; off < 1024; off <<= 1) {
        int tv = (t >= off) ? buf[t - off] : 0;
        __syncthreads();
        buf[t] += tv;
        __syncthreads();
    }
    if (t < NBUK) {
        int excl = buf[t] - v;
        bucketOff[t] = excl;
        bucketCursor[t] = excl;
        if (t == NBUK - 1) bucketOff[NBUK] = excl + v;
    }
}

// pass 3: partition edges into bucket segments (LDS rank + one reserve/bucket/block)
__global__ __launch_bounds__(256) void partition_kernel(const int* __restrict__ ei,
                                                        int* __restrict__ bucketCursor,
                                                        int2* __restrict__ pairs) {
    __shared__ int hist[NBUK];
    __shared__ int base[NBUK];
    int e0 = blockIdx.x * EPB;
    int d[EPT], s[EPT];
#pragma unroll
    for (int i = 0; i < EPT; ++i) {
        int e = e0 + i * 256 + threadIdx.x;
        bool ok = e < N_EDGES;
        d[i] = ok ? ei[N_EDGES + e] : -1;
        s[i] = ok ? ei[e] : 0;
    }
    for (int t = threadIdx.x; t < NBUK; t += 256) hist[t] = 0;
    __syncthreads();
#pragma unroll
    for (int i = 0; i < EPT; ++i)
        if (d[i] >= 0) atomicAdd(&hist[d[i] >> 7], 1);
    __syncthreads();
    for (int t = threadIdx.x; t < NBUK; t += 256)
        base[t] = hist[t] ? atomicAdd(&bucketCursor[t], hist[t]) : 0;
    __syncthreads();
    for (int t = threadIdx.x; t < NBUK; t += 256) hist[t] = 0;
    __syncthreads();
#pragma unroll
    for (int i = 0; i < EPT; ++i) {
        if (d[i] >= 0) {
            int b = d[i] >> 7;
            int r = atomicAdd(&hist[b], 1);
            pairs[base[b] + r] = make_int2(d[i], s[i]);
        }
    }
}

// pass 4: per-bucket local CSR fill (LDS deg/cursor; L2-hot col writes) + rowptr
__global__ __launch_bounds__(256) void bucket_fill_kernel(const int2* __restrict__ pairs,
                                                          const int* __restrict__ bucketOff,
                                                          int* __restrict__ rowptr,
                                                          int* __restrict__ col) {
    __shared__ int deg[128];
    __shared__ int cur[128];
    int b = blockIdx.x;
    int nbase = b << 7;
    int segB = bucketOff[b], segE = bucketOff[b + 1];
    if (threadIdx.x < 128) deg[threadIdx.x] = 0;
    __syncthreads();
    for (int e = segB + threadIdx.x; e < segE; e += 256)
        atomicAdd(&deg[pairs[e].x & 127], 1);
    __syncthreads();
    if (threadIdx.x == 0) {
        int acc = 0;
        for (int i = 0; i < 128; ++i) { cur[i] = acc; acc += deg[i]; }
    }
    __syncthreads();
    if (threadIdx.x < 128) {
        int n = nbase + threadIdx.x;
        if (n < N_NODES) rowptr[n] = segB + cur[threadIdx.x];
    }
    __syncthreads();
    for (int e = segB + threadIdx.x; e < segE; e += 256) {
        int2 p = pairs[e];
        int r = atomicAdd(&cur[p.x & 127], 1);
        col[segB + r] = p.y;
    }
    if (b == 0 && threadIdx.x == 0) rowptr[N_NODES] = N_EDGES;
}

// ---------------- weight prep / pad ----------------
__global__ __launch_bounds__(256) void prep_kernel(const float* __restrict__ conv_w,
                                                   const float* __restrict__ w_ih,
                                                   const float* __restrict__ w_hh,
                                                   const float* __restrict__ lin_w,
                                                   _Float16* __restrict__ wb) {
    int t = blockIdx.x * 256 + threadIdx.x;
    if (t >= 10 * 4096) return;
    int mat = t >> 12, idx = t & 4095, n = idx >> 6, k = idx & 63;
    float v = 0.f;
    if (n < C && k < C) {
        if (mat < 3)      v = conv_w[mat * C * C + k * C + n];
        else if (mat < 6) v = w_ih[((mat - 3) * C + n) * C + k];
        else if (mat < 9) v = w_hh[((mat - 6) * C + n) * C + k];
        else              v = lin_w[n * C + k];
    }
    wb[t] = (_Float16)v;
}

__global__ __launch_bounds__(256) void pad_x_kernel(const float* __restrict__ x,
                                                    float* __restrict__ h0) {
    int t = blockIdx.x * 256 + threadIdx.x;
    if (t >= NCP) return;
    int n = t / PC, c = t - n * PC;
    h0[t] = (c < C) ? x[n * C + c] : 0.f;
}

// ---------------- MFMA helpers ----------------
__device__ inline half8 load_a_frag(const float* __restrict__ base, int row, int ks,
                                    int lane, bool relu) {
    int kb = ks * 32 + ((lane >> 4) << 3);
    half8 r;
    if (kb >= PC) {
#pragma unroll
        for (int j = 0; j < 8; ++j) r[j] = (_Float16)0.f;
        return r;
    }
    const float* p = base + (size_t)row * PC + kb;
#pragma unroll
    for (int j = 0; j < 8; ++j) {
        float v = p[j];
        if (relu) v = v > 0.f ? v : 0.f;
        r[j] = (_Float16)v;
    }
    return r;
}

__device__ inline half8 load_b_frag(const _Float16* __restrict__ wb, int nt, int ks, int lane) {
    const _Float16* p = wb + (((nt << 4) + (lane & 15)) << 6) + (ks << 5) + ((lane >> 4) << 3);
    return *(const half8*)p;
}

__device__ inline float sigmoidf_(float x) { return 1.f / (1.f + __expf(-x)); }
__device__ inline float tanhf_(float x)    { return 2.f * sigmoidf_(2.f * x) - 1.f; }

// ---------------- dense kernels via MFMA ----------------
__global__ __launch_bounds__(256) void gemm_conv(const float* __restrict__ h,
                                                 const _Float16* __restrict__ wb,
                                                 _Float16* __restrict__ m_h) {
    int wid = threadIdx.x >> 6, lane = threadIdx.x & 63;
    int tile = blockIdx.x * 4 + wid;
    if (tile >= NTILES) return;
    int base = tile * 16;
    int arow = base + (lane & 15);
    half8 a0 = load_a_frag(h, arow, 0, lane, false);
    half8 a1 = load_a_frag(h, arow, 1, lane, false);
#pragma unroll
    for (int nt = 0; nt < 4; ++nt) {
        floatx4 acc = {0.f, 0.f, 0.f, 0.f};
        acc = __builtin_amdgcn_mfma_f32_16x16x32_f16(a0, load_b_frag(wb, nt, 0, lane), acc, 0, 0, 0);
        acc = __builtin_amdgcn_mfma_f32_16x16x32_f16(a1, load_b_frag(wb, nt, 1, lane), acc, 0, 0, 0);
        int col = (nt << 4) + (lane & 15);
#pragma unroll
        for (int e = 0; e < 4; ++e) {
            int row = base + ((lane >> 4) << 2) + e;
            m_h[(size_t)row * PH + col] = (_Float16)acc[e];
        }
    }
}

__global__ __launch_bounds__(256) void gemm_gru(const float* __restrict__ agg,
                                                const float* __restrict__ hin,
                                                const _Float16* __restrict__ wb_ih,
                                                const _Float16* __restrict__ wb_hh,
                                                const float* __restrict__ b_ih,
                                                const float* __restrict__ b_hh,
                                                float* __restrict__ hout) {
    int wid = threadIdx.x >> 6, lane = threadIdx.x & 63;
    int tile = blockIdx.x * 4 + wid;
    if (tile >= NTILES) return;
    int base = tile * 16;
    int arow = base + (lane & 15);
    half8 aA[2], aH[2];
#pragma unroll
    for (int ks = 0; ks < 2; ++ks) {
        aA[ks] = load_a_frag(agg, arow, ks, lane, false);
        aH[ks] = load_a_frag(hin, arow, ks, lane, false);
    }
    float r_[4][4], z_[4][4];
#pragma unroll
    for (int g = 0; g < 3; ++g) {
        const _Float16* wih = wb_ih + g * 4096;
        const _Float16* whh = wb_hh + g * 4096;
#pragma unroll
        for (int nt = 0; nt < 4; ++nt) {
            floatx4 accI = {0.f, 0.f, 0.f, 0.f};
            floatx4 accH = {0.f, 0.f, 0.f, 0.f};
#pragma unroll
            for (int ks = 0; ks < 2; ++ks) {
                accI = __builtin_amdgcn_mfma_f32_16x16x32_f16(aA[ks], load_b_frag(wih, nt, ks, lane), accI, 0, 0, 0);
                accH = __builtin_amdgcn_mfma_f32_16x16x32_f16(aH[ks], load_b_frag(whh, nt, ks, lane), accH, 0, 0, 0);
            }
            int col = (nt << 4) + (lane & 15);
            float bi = (col < C) ? b_ih[g * C + col] : 0.f;
            float bh = (col < C) ? b_hh[g * C + col] : 0.f;
            if (g == 0) {
#pragma unroll
                for (int e = 0; e < 4; ++e) r_[nt][e] = sigmoidf_((accI[e] + bi) + (accH[e] + bh));
            } else if (g == 1) {
#pragma unroll
                for (int e = 0; e < 4; ++e) z_[nt][e] = sigmoidf_((accI[e] + bi) + (accH[e] + bh));
            } else {
#pragma unroll
                for (int e = 0; e < 4; ++e) {
                    int row = base + ((lane >> 4) << 2) + e;
                    if (col < C) {
                        float hv = hin[(size_t)row * PC + col];
                        float nn = tanhf_((accI[e] + bi) + r_[nt][e] * (accH[e] + bh));
                        float z = z_[nt][e];
                        hout[(size_t)row * PC + col] = (1.f - z) * nn + z * hv;
                    } else if (col < PC) {
                        hout[(size_t)row * PC + col] = 0.f;
                    }
                }
            }
        }
    }
}

__global__ __launch_bounds__(256) void gemm_out(const float* __restrict__ h,
                                                const _Float16* __restrict__ wb,
                                                const float* __restrict__ lin_b,
                                                float* __restrict__ out) {
    int wid = threadIdx.x >> 6, lane = threadIdx.x & 63;
    int tile = blockIdx.x * 4 + wid;
    if (tile >= NTILES) return;
    int base = tile * 16;
    int arow = base + (lane & 15);
    half8 a0 = load_a_frag(h, arow, 0, lane, true);
    half8 a1 = load_a_frag(h, arow, 1, lane, true);
#pragma unroll
    for (int nt = 0; nt < 4; ++nt) {
        floatx4 acc = {0.f, 0.f, 0.f, 0.f};
        acc = __builtin_amdgcn_mfma_f32_16x16x32_f16(a0, load_b_frag(wb, nt, 0, lane), acc, 0, 0, 0);
        acc = __builtin_amdgcn_mfma_f32_16x16x32_f16(a1, load_b_frag(wb, nt, 1, lane), acc, 0, 0, 0);
        int col = (nt << 4) + (lane & 15);
        if (col < C) {
            float b = lin_b[col];
#pragma unroll
            for (int e = 0; e < 4; ++e) {
                int row = base + ((lane >> 4) << 2) + e;
                out[(size_t)row * C + col] = acc[e] + b;
            }
        }
    }
}

// ---------------- gather (unchanged) ----------------
__global__ __launch_bounds__(256) void gather_kernel(const __half* __restrict__ m_h,
                                                     const int* __restrict__ rowptr,
                                                     const int* __restrict__ col,
                                                     float* __restrict__ agg) {
    int w = (blockIdx.x * 256 + threadIdx.x) >> 6;
    int lane = threadIdx.x & 63;
    if (w >= N_NODES) return;
    int start = rowptr[w], end = rowptr[w + 1];
    int j = lane >> 3, q = lane & 7;
    bool qok = (q < 7);
    int hoff = qok ? (q * 8) : 48;
    float acc0 = 0.f, acc1 = 0.f, acc2 = 0.f, acc3 = 0.f;
    float acc4 = 0.f, acc5 = 0.f, acc6 = 0.f, acc7 = 0.f;

    for (int base = start; base < end; base += 64) {
        int cidx = base + lane;
        int cols = col[cidx < N_EDGES ? cidx : (N_EDGES - 1)];
        int cnt = end - base; if (cnt > 64) cnt = 64;
        int nt8 = (cnt + 7) >> 3;
#pragma unroll 4
        for (int t = 0; t < nt8; ++t) {
            int rel = 8 * t + j;
            int s = __shfl(cols, rel);
            bool valid = qok && (rel < cnt);
            const uint4 v = *reinterpret_cast<const uint4*>(m_h + (size_t)s * PH + hoff);
            float2 f0 = __half22float2(*reinterpret_cast<const __half2*>(&v.x));
            float2 f1 = __half22float2(*reinterpret_cast<const __half2*>(&v.y));
            float2 f2 = __half22float2(*reinterpret_cast<const __half2*>(&v.z));
            float2 f3 = __half22float2(*reinterpret_cast<const __half2*>(&v.w));
            acc0 += valid ? f0.x : 0.f;  acc1 += valid ? f0.y : 0.f;
            acc2 += valid ? f1.x : 0.f;  acc3 += valid ? f1.y : 0.f;
            acc4 += valid ? f2.x : 0.f;  acc5 += valid ? f2.y : 0.f;
            acc6 += valid ? f3.x : 0.f;  acc7 += valid ? f3.y : 0.f;
        }
    }
#pragma unroll
    for (int s = 8; s <= 32; s <<= 1) {
        acc0 += __shfl_xor(acc0, s); acc1 += __shfl_xor(acc1, s);
        acc2 += __shfl_xor(acc2, s); acc3 += __shfl_xor(acc3, s);
        acc4 += __shfl_xor(acc4, s); acc5 += __shfl_xor(acc5, s);
        acc6 += __shfl_xor(acc6, s); acc7 += __shfl_xor(acc7, s);
    }
    if (j == 0 && qok) {
        float* ar = agg + (size_t)w * PC + q * 8;
        *reinterpret_cast<float4*>(ar)     = make_float4(acc0, acc1, acc2, acc3);
        *reinterpret_cast<float4*>(ar + 4) = make_float4(acc4, acc5, acc6, acc7);
    }
}

extern "C" void kernel_launch(void* const* d_in, const int* in_sizes, int n_in,
                              void* d_out, int out_size, void* d_ws, size_t ws_size,
                              hipStream_t stream) {
    const float* x      = (const float*)d_in[0];
    const int*   ei     = (const int*)  d_in[1];
    const float* conv_w = (const float*)d_in[3];
    const float* w_ih   = (const float*)d_in[4];
    const float* w_hh   = (const float*)d_in[5];
    const float* b_ih   = (const float*)d_in[6];
    const float* b_hh   = (const float*)d_in[7];
    const float* lin_w  = (const float*)d_in[9];
    const float* lin_b  = (const float*)d_in[10];
    float* out = (float*)d_out;

    // layout: h0 | agg | h1 | m_h | wb | col | rowptr | bucket arrays
    // pairs (25.6 MB) aliases agg + head of h1 (dead before first gather)
    float* ws  = (float*)d_ws;
    float* h0  = ws;
    float* agg = ws + NCP;
    float* h1  = ws + 2 * (size_t)NCP;
    int2* pairs = (int2*)agg;
    _Float16* m_h = (_Float16*)(ws + 3 * (size_t)NCP);
    _Float16* wb  = m_h + (size_t)N_NODES * PH;
    int* col          = (int*)(wb + 10 * 4096);
    int* rowptr       = col + N_EDGES;             // N_NODES+1
    int* bucketCnt    = rowptr + N_NODES + 1;      // NBUK
    int* bucketOff    = bucketCnt + NBUK;          // NBUK+1
    int* bucketCursor = bucketOff + NBUK + 1;      // NBUK

    const int nodeBlocksP = (NCP + 255) / 256;
    const int waveBlocks  = (N_NODES * 64 + 255) / 256;
    const int gemmBlocks  = (NTILES + 3) / 4;

    // prep + pad
    prep_kernel<<<160, 256, 0, stream>>>(conv_w, w_ih, w_hh, lin_w, wb);
    pad_x_kernel<<<nodeBlocksP, 256, 0, stream>>>(x, h0);

    // bucket-sorted CSR build
    hipMemsetAsync(bucketCnt, 0, NBUK * sizeof(int), stream);
    bhist_kernel<<<EB, 256, 0, stream>>>(ei, bucketCnt);
    bscan_kernel<<<1, 1024, 0, stream>>>(bucketCnt, bucketOff, bucketCursor);
    partition_kernel<<<EB, 256, 0, stream>>>(ei, bucketCursor, pairs);
    bucket_fill_kernel<<<NBUK, 256, 0, stream>>>(pairs, bucketOff, rowptr, col);

    // 3 layers
    gemm_conv<<<gemmBlocks, 256, 0, stream>>>(h0, wb + 0 * 4096, m_h);
    gather_kernel<<<waveBlocks, 256, 0, stream>>>((const __half*)m_h, rowptr, col, agg);
    gemm_gru<<<gemmBlocks, 256, 0, stream>>>(agg, h0, wb + 3 * 4096, wb + 6 * 4096, b_ih, b_hh, h1);

    gemm_conv<<<gemmBlocks, 256, 0, stream>>>(h1, wb + 1 * 4096, m_h);
    gather_kernel<<<waveBlocks, 256, 0, stream>>>((const __half*)m_h, rowptr, col, agg);
    gemm_gru<<<gemmBlocks, 256, 0, stream>>>(agg, h1, wb + 3 * 4096, wb + 6 * 4096, b_ih, b_hh, h0);

    gemm_conv<<<gemmBlocks, 256, 0, stream>>>(h0, wb + 2 * 4096, m_h);
    gather_kernel<<<waveBlocks, 256, 0, stream>>>((const __half*)m_h, rowptr, col, agg);
    gemm_gru<<<gemmBlocks, 256, 0, stream>>>(agg, h0, wb + 3 * 4096, wb + 6 * 4096, b_ih, b_hh, h1);

    gemm_out<<<gemmBlocks, 256, 0, stream>>>(h1, wb + 9 * 4096, lin_b, out);
}

// Round 16
// 483.144 us; speedup vs baseline: 4.0161x; 1.0674x over previous
//
#include <hip/hip_runtime.h>
#include <hip/hip_fp16.h>

#define N_NODES 100000
#define N_EDGES 3200000
#define C 50
#define PC 56          // padded fp32 row for h/agg (224 B)
#define PH 64          // padded fp16 row for m (128 B)
#define NC (N_NODES * C)
#define NCP (N_NODES * PC)
#define NTILES (N_NODES / 16)                 // 6250
#define NBUK ((N_NODES + 127) / 128)          // 782 buckets of 128 nodes
#define BCAP 4608                             // padded slots per bucket (mean 4092 + 8 sigma)
#define EPB 4096                              // edges per block (partition)
#define EB  ((N_EDGES + EPB - 1) / EPB)       // 782
#define EPT (EPB / 256)                       // 16 edges per thread

typedef _Float16 half8 __attribute__((ext_vector_type(8)));
typedef float floatx4 __attribute__((ext_vector_type(4)));

// ---------------- bucket-sorted CSR build (no pre-count pass) ----------------

// partition edges into PADDED bucket segments; cnt[b] = exact bucket size.
// packed pair: p = (src << 7) | (dst & 127)   (src < 2^17, fits 24 bits)
__global__ __launch_bounds__(256) void partition_kernel(const int* __restrict__ ei,
                                                        int* __restrict__ cnt,
                                                        unsigned int* __restrict__ pairs) {
    __shared__ int hist[NBUK];
    __shared__ int base[NBUK];
    int e0 = blockIdx.x * EPB;
    int b[EPT]; unsigned int p[EPT];
#pragma unroll
    for (int i = 0; i < EPT; ++i) {
        int e = e0 + i * 256 + threadIdx.x;
        bool ok = e < N_EDGES;
        int d = ok ? ei[N_EDGES + e] : 0;
        int s = ok ? ei[e] : 0;
        b[i] = ok ? (d >> 7) : -1;
        p[i] = ((unsigned)s << 7) | (unsigned)(d & 127);
    }
    for (int t = threadIdx.x; t < NBUK; t += 256) hist[t] = 0;
    __syncthreads();
#pragma unroll
    for (int i = 0; i < EPT; ++i)
        if (b[i] >= 0) atomicAdd(&hist[b[i]], 1);
    __syncthreads();
    for (int t = threadIdx.x; t < NBUK; t += 256)
        base[t] = hist[t] ? (t * BCAP + atomicAdd(&cnt[t], hist[t])) : 0;
    __syncthreads();
    for (int t = threadIdx.x; t < NBUK; t += 256) hist[t] = 0;
    __syncthreads();
#pragma unroll
    for (int i = 0; i < EPT; ++i) {
        if (b[i] >= 0) {
            int r = atomicAdd(&hist[b[i]], 1);
            pairs[base[b[i]] + r] = p[i];
        }
    }
}

// exclusive scan of cnt (782) -> bucketOff[0..NBUK]
__global__ __launch_bounds__(1024) void bscan_kernel(const int* __restrict__ cnt,
                                                     int* __restrict__ bucketOff) {
    __shared__ int buf[1024];
    int t = threadIdx.x;
    int v = (t < NBUK) ? cnt[t] : 0;
    buf[t] = v;
    __syncthreads();
    for (int off = 1; off < 1024; off <<= 1) {
        int tv = (t >= off) ? buf[t - off] : 0;
        __syncthreads();
        buf[t] += tv;
        __syncthreads();
    }
    if (t < NBUK) {
        int excl = buf[t] - v;
        bucketOff[t] = excl;
        if (t == NBUK - 1) bucketOff[NBUK] = excl + v;
    }
}

// per-bucket local CSR fill from padded slots; compact col; emit rowptr
__global__ __launch_bounds__(256) void bucket_fill_kernel(const unsigned int* __restrict__ pairs,
                                                          const int* __restrict__ cnt,
                                                          const int* __restrict__ bucketOff,
                                                          int* __restrict__ rowptr,
                                                          int* __restrict__ col) {
    __shared__ int deg[128];
    __shared__ int cur[128];
    int b = blockIdx.x;
    int nbase = b << 7;
    int n_e = cnt[b];
    int slot0 = b * BCAP;
    int segB = bucketOff[b];
    if (threadIdx.x < 128) deg[threadIdx.x] = 0;
    __syncthreads();
    for (int e = threadIdx.x; e < n_e; e += 256)
        atomicAdd(&deg[pairs[slot0 + e] & 127], 1);
    __syncthreads();
    if (threadIdx.x == 0) {
        int acc = 0;
        for (int i = 0; i < 128; ++i) { cur[i] = acc; acc += deg[i]; }
    }
    __syncthreads();
    if (threadIdx.x < 128) {
        int n = nbase + threadIdx.x;
        if (n < N_NODES) rowptr[n] = segB + cur[threadIdx.x];
    }
    __syncthreads();
    for (int e = threadIdx.x; e < n_e; e += 256) {
        unsigned int p = pairs[slot0 + e];
        int r = atomicAdd(&cur[p & 127], 1);
        col[segB + r] = (int)(p >> 7);
    }
    if (b == 0 && threadIdx.x == 0) rowptr[N_NODES] = N_EDGES;
}

// ---------------- weight prep / pad ----------------
__global__ __launch_bounds__(256) void prep_kernel(const float* __restrict__ conv_w,
                                                   const float* __restrict__ w_ih,
                                                   const float* __restrict__ w_hh,
                                                   const float* __restrict__ lin_w,
                                                   _Float16* __restrict__ wb) {
    int t = blockIdx.x * 256 + threadIdx.x;
    if (t >= 10 * 4096) return;
    int mat = t >> 12, idx = t & 4095, n = idx >> 6, k = idx & 63;
    float v = 0.f;
    if (n < C && k < C) {
        if (mat < 3)      v = conv_w[mat * C * C + k * C + n];
        else if (mat < 6) v = w_ih[((mat - 3) * C + n) * C + k];
        else if (mat < 9) v = w_hh[((mat - 6) * C + n) * C + k];
        else              v = lin_w[n * C + k];
    }
    wb[t] = (_Float16)v;
}

__global__ __launch_bounds__(256) void pad_x_kernel(const float* __restrict__ x,
                                                    float* __restrict__ h0) {
    int t = blockIdx.x * 256 + threadIdx.x;
    if (t >= NCP) return;
    int n = t / PC, c = t - n * PC;
    h0[t] = (c < C) ? x[n * C + c] : 0.f;
}

// ---------------- MFMA helpers ----------------
__device__ inline half8 load_a_frag(const float* __restrict__ base, int row, int ks,
                                    int lane, bool relu) {
    int kb = ks * 32 + ((lane >> 4) << 3);
    half8 r;
    if (kb >= PC) {
#pragma unroll
        for (int j = 0; j < 8; ++j) r[j] = (_Float16)0.f;
        return r;
    }
    const float* p = base + (size_t)row * PC + kb;
#pragma unroll
    for (int j = 0; j < 8; ++j) {
        float v = p[j];
        if (relu) v = v > 0.f ? v : 0.f;
        r[j] = (_Float16)v;
    }
    return r;
}

__device__ inline half8 load_b_frag(const _Float16* __restrict__ wb, int nt, int ks, int lane) {
    const _Float16* p = wb + (((nt << 4) + (lane & 15)) << 6) + (ks << 5) + ((lane >> 4) << 3);
    return *(const half8*)p;
}

__device__ inline float sigmoidf_(float x) { return 1.f / (1.f + __expf(-x)); }
__device__ inline float tanhf_(float x)    { return 2.f * sigmoidf_(2.f * x) - 1.f; }

// ---------------- dense kernels via MFMA ----------------
__global__ __launch_bounds__(256) void gemm_conv(const float* __restrict__ h,
                                                 const _Float16* __restrict__ wb,
                                                 _Float16* __restrict__ m_h) {
    int wid = threadIdx.x >> 6, lane = threadIdx.x & 63;
    int tile = blockIdx.x * 4 + wid;
    if (tile >= NTILES) return;
    int base = tile * 16;
    int arow = base + (lane & 15);
    half8 a0 = load_a_frag(h, arow, 0, lane, false);
    half8 a1 = load_a_frag(h, arow, 1, lane, false);
#pragma unroll
    for (int nt = 0; nt < 4; ++nt) {
        floatx4 acc = {0.f, 0.f, 0.f, 0.f};
        acc = __builtin_amdgcn_mfma_f32_16x16x32_f16(a0, load_b_frag(wb, nt, 0, lane), acc, 0, 0, 0);
        acc = __builtin_amdgcn_mfma_f32_16x16x32_f16(a1, load_b_frag(wb, nt, 1, lane), acc, 0, 0, 0);
        int col = (nt << 4) + (lane & 15);
#pragma unroll
        for (int e = 0; e < 4; ++e) {
            int row = base + ((lane >> 4) << 2) + e;
            m_h[(size_t)row * PH + col] = (_Float16)acc[e];
        }
    }
}

__global__ __launch_bounds__(256) void gemm_gru(const float* __restrict__ agg,
                                                const float* __restrict__ hin,
                                                const _Float16* __restrict__ wb_ih,
                                                const _Float16* __restrict__ wb_hh,
                                                const float* __restrict__ b_ih,
                                                const float* __restrict__ b_hh,
                                                float* __restrict__ hout) {
    int wid = threadIdx.x >> 6, lane = threadIdx.x & 63;
    int tile = blockIdx.x * 4 + wid;
    if (tile >= NTILES) return;
    int base = tile * 16;
    int arow = base + (lane & 15);
    half8 aA[2], aH[2];
#pragma unroll
    for (int ks = 0; ks < 2; ++ks) {
        aA[ks] = load_a_frag(agg, arow, ks, lane, false);
        aH[ks] = load_a_frag(hin, arow, ks, lane, false);
    }
    float r_[4][4], z_[4][4];
#pragma unroll
    for (int g = 0; g < 3; ++g) {
        const _Float16* wih = wb_ih + g * 4096;
        const _Float16* whh = wb_hh + g * 4096;
#pragma unroll
        for (int nt = 0; nt < 4; ++nt) {
            floatx4 accI = {0.f, 0.f, 0.f, 0.f};
            floatx4 accH = {0.f, 0.f, 0.f, 0.f};
#pragma unroll
            for (int ks = 0; ks < 2; ++ks) {
                accI = __builtin_amdgcn_mfma_f32_16x16x32_f16(aA[ks], load_b_frag(wih, nt, ks, lane), accI, 0, 0, 0);
                accH = __builtin_amdgcn_mfma_f32_16x16x32_f16(aH[ks], load_b_frag(whh, nt, ks, lane), accH, 0, 0, 0);
            }
            int col = (nt << 4) + (lane & 15);
            float bi = (col < C) ? b_ih[g * C + col] : 0.f;
            float bh = (col < C) ? b_hh[g * C + col] : 0.f;
            if (g == 0) {
#pragma unroll
                for (int e = 0; e < 4; ++e) r_[nt][e] = sigmoidf_((accI[e] + bi) + (accH[e] + bh));
            } else if (g == 1) {
#pragma unroll
                for (int e = 0; e < 4; ++e) z_[nt][e] = sigmoidf_((accI[e] + bi) + (accH[e] + bh));
            } else {
#pragma unroll
                for (int e = 0; e < 4; ++e) {
                    int row = base + ((lane >> 4) << 2) + e;
                    if (col < C) {
                        float hv = hin[(size_t)row * PC + col];
                        float nn = tanhf_((accI[e] + bi) + r_[nt][e] * (accH[e] + bh));
                        float z = z_[nt][e];
                        hout[(size_t)row * PC + col] = (1.f - z) * nn + z * hv;
                    } else if (col < PC) {
                        hout[(size_t)row * PC + col] = 0.f;
                    }
                }
            }
        }
    }
}

__global__ __launch_bounds__(256) void gemm_out(const float* __restrict__ h,
                                                const _Float16* __restrict__ wb,
                                                const float* __restrict__ lin_b,
                                                float* __restrict__ out) {
    int wid = threadIdx.x >> 6, lane = threadIdx.x & 63;
    int tile = blockIdx.x * 4 + wid;
    if (tile >= NTILES) return;
    int base = tile * 16;
    int arow = base + (lane & 15);
    half8 a0 = load_a_frag(h, arow, 0, lane, true);
    half8 a1 = load_a_frag(h, arow, 1, lane, true);
#pragma unroll
    for (int nt = 0; nt < 4; ++nt) {
        floatx4 acc = {0.f, 0.f, 0.f, 0.f};
        acc = __builtin_amdgcn_mfma_f32_16x16x32_f16(a0, load_b_frag(wb, nt, 0, lane), acc, 0, 0, 0);
        acc = __builtin_amdgcn_mfma_f32_16x16x32_f16(a1, load_b_frag(wb, nt, 1, lane), acc, 0, 0, 0);
        int col = (nt << 4) + (lane & 15);
        if (col < C) {
            float b = lin_b[col];
#pragma unroll
            for (int e = 0; e < 4; ++e) {
                int row = base + ((lane >> 4) << 2) + e;
                out[(size_t)row * C + col] = acc[e] + b;
            }
        }
    }
}

// ---------------- gather (unchanged) ----------------
__global__ __launch_bounds__(256) void gather_kernel(const __half* __restrict__ m_h,
                                                     const int* __restrict__ rowptr,
                                                     const int* __restrict__ col,
                                                     float* __restrict__ agg) {
    int w = (blockIdx.x * 256 + threadIdx.x) >> 6;
    int lane = threadIdx.x & 63;
    if (w >= N_NODES) return;
    int start = rowptr[w], end = rowptr[w + 1];
    int j = lane >> 3, q = lane & 7;
    bool qok = (q < 7);
    int hoff = qok ? (q * 8) : 48;
    float acc0 = 0.f, acc1 = 0.f, acc2 = 0.f, acc3 = 0.f;
    float acc4 = 0.f, acc5 = 0.f, acc6 = 0.f, acc7 = 0.f;

    for (int base = start; base < end; base += 64) {
        int cidx = base + lane;
        int cols = col[cidx < N_EDGES ? cidx : (N_EDGES - 1)];
        int cnt = end - base; if (cnt > 64) cnt = 64;
        int nt8 = (cnt + 7) >> 3;
#pragma unroll 4
        for (int t = 0; t < nt8; ++t) {
            int rel = 8 * t + j;
            int s = __shfl(cols, rel);
            bool valid = qok && (rel < cnt);
            const uint4 v = *reinterpret_cast<const uint4*>(m_h + (size_t)s * PH + hoff);
            float2 f0 = __half22float2(*reinterpret_cast<const __half2*>(&v.x));
            float2 f1 = __half22float2(*reinterpret_cast<const __half2*>(&v.y));
            float2 f2 = __half22float2(*reinterpret_cast<const __half2*>(&v.z));
            float2 f3 = __half22float2(*reinterpret_cast<const __half2*>(&v.w));
            acc0 += valid ? f0.x : 0.f;  acc1 += valid ? f0.y : 0.f;
            acc2 += valid ? f1.x : 0.f;  acc3 += valid ? f1.y : 0.f;
            acc4 += valid ? f2.x : 0.f;  acc5 += valid ? f2.y : 0.f;
            acc6 += valid ? f3.x : 0.f;  acc7 += valid ? f3.y : 0.f;
        }
    }
#pragma unroll
    for (int s = 8; s <= 32; s <<= 1) {
        acc0 += __shfl_xor(acc0, s); acc1 += __shfl_xor(acc1, s);
        acc2 += __shfl_xor(acc2, s); acc3 += __shfl_xor(acc3, s);
        acc4 += __shfl_xor(acc4, s); acc5 += __shfl_xor(acc5, s);
        acc6 += __shfl_xor(acc6, s); acc7 += __shfl_xor(acc7, s);
    }
    if (j == 0 && qok) {
        float* ar = agg + (size_t)w * PC + q * 8;
        *reinterpret_cast<float4*>(ar)     = make_float4(acc0, acc1, acc2, acc3);
        *reinterpret_cast<float4*>(ar + 4) = make_float4(acc4, acc5, acc6, acc7);
    }
}

extern "C" void kernel_launch(void* const* d_in, const int* in_sizes, int n_in,
                              void* d_out, int out_size, void* d_ws, size_t ws_size,
                              hipStream_t stream) {
    const float* x      = (const float*)d_in[0];
    const int*   ei     = (const int*)  d_in[1];
    const float* conv_w = (const float*)d_in[3];
    const float* w_ih   = (const float*)d_in[4];
    const float* w_hh   = (const float*)d_in[5];
    const float* b_ih   = (const float*)d_in[6];
    const float* b_hh   = (const float*)d_in[7];
    const float* lin_w  = (const float*)d_in[9];
    const float* lin_b  = (const float*)d_in[10];
    float* out = (float*)d_out;

    // layout: h0 | agg | h1 | m_h | wb | col | rowptr | cnt | bucketOff
    // padded pairs (14.4 MB) aliases agg (22.4 MB; dead before first gather)
    float* ws  = (float*)d_ws;
    float* h0  = ws;
    float* agg = ws + NCP;
    float* h1  = ws + 2 * (size_t)NCP;
    unsigned int* pairs = (unsigned int*)agg;
    _Float16* m_h = (_Float16*)(ws + 3 * (size_t)NCP);
    _Float16* wb  = m_h + (size_t)N_NODES * PH;
    int* col       = (int*)(wb + 10 * 4096);
    int* rowptr    = col + N_EDGES;             // N_NODES+1
    int* cnt       = rowptr + N_NODES + 1;      // NBUK
    int* bucketOff = cnt + NBUK;                // NBUK+1

    const int nodeBlocksP = (NCP + 255) / 256;
    const int waveBlocks  = (N_NODES * 64 + 255) / 256;
    const int gemmBlocks  = (NTILES + 3) / 4;

    // prep + pad
    prep_kernel<<<160, 256, 0, stream>>>(conv_w, w_ih, w_hh, lin_w, wb);
    pad_x_kernel<<<nodeBlocksP, 256, 0, stream>>>(x, h0);

    // bucket-sorted CSR build (padded buckets, no pre-count pass)
    hipMemsetAsync(cnt, 0, NBUK * sizeof(int), stream);
    partition_kernel<<<EB, 256, 0, stream>>>(ei, cnt, pairs);
    bscan_kernel<<<1, 1024, 0, stream>>>(cnt, bucketOff);
    bucket_fill_kernel<<<NBUK, 256, 0, stream>>>(pairs, cnt, bucketOff, rowptr, col);

    // 3 layers
    gemm_conv<<<gemmBlocks, 256, 0, stream>>>(h0, wb + 0 * 4096, m_h);
    gather_kernel<<<waveBlocks, 256, 0, stream>>>((const __half*)m_h, rowptr, col, agg);
    gemm_gru<<<gemmBlocks, 256, 0, stream>>>(agg, h0, wb + 3 * 4096, wb + 6 * 4096, b_ih, b_hh, h1);

    gemm_conv<<<gemmBlocks, 256, 0, stream>>>(h1, wb + 1 * 4096, m_h);
    gather_kernel<<<waveBlocks, 256, 0, stream>>>((const __half*)m_h, rowptr, col, agg);
    gemm_gru<<<gemmBlocks, 256, 0, stream>>>(agg, h1, wb + 3 * 4096, wb + 6 * 4096, b_ih, b_hh, h0);

    gemm_conv<<<gemmBlocks, 256, 0, stream>>>(h0, wb + 2 * 4096, m_h);
    gather_kernel<<<waveBlocks, 256, 0, stream>>>((const __half*)m_h, rowptr, col, agg);
    gemm_gru<<<gemmBlocks, 256, 0, stream>>>(agg, h0, wb + 3 * 4096, wb + 6 * 4096, b_ih, b_hh, h1);

    gemm_out<<<gemmBlocks, 256, 0, stream>>>(h1, wb + 9 * 4096, lin_b, out);
}

// Round 18
// 459.363 us; speedup vs baseline: 4.2240x; 1.0518x over previous
//
#include <hip/hip_runtime.h>
#include <hip/hip_fp16.h>

#define N_NODES 100000
#define N_EDGES 3200000
#define C 50
#define PH 64          // fp16 row stride for h/agg/m (128 B)
#define NH (N_NODES * PH)
#define NTILES (N_NODES / 16)                 // 6250
#define NBUK ((N_NODES + 127) / 128)          // 782 buckets of 128 nodes
#define BCAP 4608                             // padded slots per bucket
#define EPB 4096                              // edges per block (partition)
#define EB  ((N_EDGES + EPB - 1) / EPB)       // 782
#define EPT (EPB / 256)                       // 16 edges per thread

typedef _Float16 half8 __attribute__((ext_vector_type(8)));
typedef float floatx4 __attribute__((ext_vector_type(4)));

// ---------------- bucket-sorted CSR build ----------------

// partition edges into PADDED bucket segments; cnt[b] = exact bucket size.
// packed pair: p = (src << 7) | (dst & 127)
__global__ __launch_bounds__(256) void partition_kernel(const int* __restrict__ ei,
                                                        int* __restrict__ cnt,
                                                        unsigned int* __restrict__ pairs) {
    __shared__ int hist[NBUK];
    __shared__ int base[NBUK];
    int e0 = blockIdx.x * EPB;
    int b[EPT]; unsigned int p[EPT];
#pragma unroll
    for (int i = 0; i < EPT; ++i) {
        int e = e0 + i * 256 + threadIdx.x;
        bool ok = e < N_EDGES;
        int d = ok ? ei[N_EDGES + e] : 0;
        int s = ok ? ei[e] : 0;
        b[i] = ok ? (d >> 7) : -1;
        p[i] = ((unsigned)s << 7) | (unsigned)(d & 127);
    }
    for (int t = threadIdx.x; t < NBUK; t += 256) hist[t] = 0;
    __syncthreads();
#pragma unroll
    for (int i = 0; i < EPT; ++i)
        if (b[i] >= 0) atomicAdd(&hist[b[i]], 1);
    __syncthreads();
    for (int t = threadIdx.x; t < NBUK; t += 256)
        base[t] = hist[t] ? (t * BCAP + atomicAdd(&cnt[t], hist[t])) : 0;
    __syncthreads();
    for (int t = threadIdx.x; t < NBUK; t += 256) hist[t] = 0;
    __syncthreads();
#pragma unroll
    for (int i = 0; i < EPT; ++i) {
        if (b[i] >= 0) {
            int r = atomicAdd(&hist[b[i]], 1);
            pairs[base[b[i]] + r] = p[i];
        }
    }
}

// exclusive scan of cnt (782) -> bucketOff[0..NBUK]
__global__ __launch_bounds__(1024) void bscan_kernel(const int* __restrict__ cnt,
                                                     int* __restrict__ bucketOff) {
    __shared__ int buf[1024];
    int t = threadIdx.x;
    int v = (t < NBUK) ? cnt[t] : 0;
    buf[t] = v;
    __syncthreads();
    for (int off = 1; off < 1024; off <<= 1) {
        int tv = (t >= off) ? buf[t - off] : 0;
        __syncthreads();
        buf[t] += tv;
        __syncthreads();
    }
    if (t < NBUK) {
        int excl = buf[t] - v;
        bucketOff[t] = excl;
        if (t == NBUK - 1) bucketOff[NBUK] = excl + v;
    }
}

// per-bucket local CSR fill from padded slots; compact col; emit rowptr
__global__ __launch_bounds__(256) void bucket_fill_kernel(const unsigned int* __restrict__ pairs,
                                                          const int* __restrict__ cnt,
                                                          const int* __restrict__ bucketOff,
                                                          int* __restrict__ rowptr,
                                                          int* __restrict__ col) {
    __shared__ int deg[128];
    __shared__ int cur[128];
    int b = blockIdx.x;
    int nbase = b << 7;
    int n_e = cnt[b];
    int slot0 = b * BCAP;
    int segB = bucketOff[b];
    if (threadIdx.x < 128) deg[threadIdx.x] = 0;
    __syncthreads();
    for (int e = threadIdx.x; e < n_e; e += 256)
        atomicAdd(&deg[pairs[slot0 + e] & 127], 1);
    __syncthreads();
    if (threadIdx.x == 0) {
        int acc = 0;
        for (int i = 0; i < 128; ++i) { cur[i] = acc; acc += deg[i]; }
    }
    __syncthreads();
    if (threadIdx.x < 128) {
        int n = nbase + threadIdx.x;
        if (n < N_NODES) rowptr[n] = segB + cur[threadIdx.x];
    }
    __syncthreads();
    for (int e = threadIdx.x; e < n_e; e += 256) {
        unsigned int p = pairs[slot0 + e];
        int r = atomicAdd(&cur[p & 127], 1);
        col[segB + r] = (int)(p >> 7);
    }
    if (b == 0 && threadIdx.x == 0) rowptr[N_NODES] = N_EDGES;
}

// ---------------- fused setup: pad x -> h0 (fp16), weight prep, cnt zero ----------------
__global__ __launch_bounds__(256) void init_kernel(const float* __restrict__ x,
                                                   const float* __restrict__ conv_w,
                                                   const float* __restrict__ w_ih,
                                                   const float* __restrict__ w_hh,
                                                   const float* __restrict__ lin_w,
                                                   _Float16* __restrict__ h0,
                                                   _Float16* __restrict__ wb,
                                                   int* __restrict__ cnt) {
    int t = blockIdx.x * 256 + threadIdx.x;
    if (t < NH) {
        int n = t >> 6, c = t & 63;
        h0[t] = (c < C) ? (_Float16)x[n * C + c] : (_Float16)0.f;
    }
    if (t < 10 * 4096) {
        int mat = t >> 12, idx = t & 4095, n = idx >> 6, k = idx & 63;
        float v = 0.f;
        if (n < C && k < C) {
            if (mat < 3)      v = conv_w[mat * C * C + k * C + n];
            else if (mat < 6) v = w_ih[((mat - 3) * C + n) * C + k];
            else if (mat < 9) v = w_hh[((mat - 6) * C + n) * C + k];
            else              v = lin_w[n * C + k];
        }
        wb[t] = (_Float16)v;
    }
    if (t < NBUK) cnt[t] = 0;
}

// ---------------- MFMA helpers (fp16 [*][64] rows) ----------------
__device__ inline half8 load_a16(const _Float16* __restrict__ base, int row, int ks, int lane) {
    return *(const half8*)(base + (size_t)row * PH + (ks << 5) + ((lane >> 4) << 3));
}

__device__ inline half8 load_b_frag(const _Float16* __restrict__ wb, int nt, int ks, int lane) {
    const _Float16* p = wb + (((nt << 4) + (lane & 15)) << 6) + (ks << 5) + ((lane >> 4) << 3);
    return *(const half8*)p;
}

__device__ inline float sigmoidf_(float x) { return 1.f / (1.f + __expf(-x)); }
__device__ inline float tanhf_(float x)    { return 2.f * sigmoidf_(2.f * x) - 1.f; }

// ---------------- dense kernels via MFMA ----------------
__global__ __launch_bounds__(256) void gemm_conv(const _Float16* __restrict__ h,
                                                 const _Float16* __restrict__ wb,
                                                 _Float16* __restrict__ m_h) {
    int wid = threadIdx.x >> 6, lane = threadIdx.x & 63;
    int tile = blockIdx.x * 4 + wid;
    if (tile >= NTILES) return;
    int base = tile * 16;
    int arow = base + (lane & 15);
    half8 a0 = load_a16(h, arow, 0, lane);
    half8 a1 = load_a16(h, arow, 1, lane);
#pragma unroll
    for (int nt = 0; nt < 4; ++nt) {
        floatx4 acc = {0.f, 0.f, 0.f, 0.f};
        acc = __builtin_amdgcn_mfma_f32_16x16x32_f16(a0, load_b_frag(wb, nt, 0, lane), acc, 0, 0, 0);
        acc = __builtin_amdgcn_mfma_f32_16x16x32_f16(a1, load_b_frag(wb, nt, 1, lane), acc, 0, 0, 0);
        int col = (nt << 4) + (lane & 15);
#pragma unroll
        for (int e = 0; e < 4; ++e) {
            int row = base + ((lane >> 4) << 2) + e;
            m_h[(size_t)row * PH + col] = (_Float16)acc[e];
        }
    }
}

__global__ __launch_bounds__(256) void gemm_gru(const _Float16* __restrict__ agg,
                                                const _Float16* __restrict__ hin,
                                                const _Float16* __restrict__ wb_ih,
                                                const _Float16* __restrict__ wb_hh,
                                                const float* __restrict__ b_ih,
                                                const float* __restrict__ b_hh,
                                                _Float16* __restrict__ hout) {
    int wid = threadIdx.x >> 6, lane = threadIdx.x & 63;
    int tile = blockIdx.x * 4 + wid;
    if (tile >= NTILES) return;
    int base = tile * 16;
    int arow = base + (lane & 15);
    half8 aA[2], aH[2];
#pragma unroll
    for (int ks = 0; ks < 2; ++ks) {
        aA[ks] = load_a16(agg, arow, ks, lane);
        aH[ks] = load_a16(hin, arow, ks, lane);
    }
    float r_[4][4], z_[4][4];
#pragma unroll
    for (int g = 0; g < 3; ++g) {
        const _Float16* wih = wb_ih + g * 4096;
        const _Float16* whh = wb_hh + g * 4096;
#pragma unroll
        for (int nt = 0; nt < 4; ++nt) {
            floatx4 accI = {0.f, 0.f, 0.f, 0.f};
            floatx4 accH = {0.f, 0.f, 0.f, 0.f};
#pragma unroll
            for (int ks = 0; ks < 2; ++ks) {
                accI = __builtin_amdgcn_mfma_f32_16x16x32_f16(aA[ks], load_b_frag(wih, nt, ks, lane), accI, 0, 0, 0);
                accH = __builtin_amdgcn_mfma_f32_16x16x32_f16(aH[ks], load_b_frag(whh, nt, ks, lane), accH, 0, 0, 0);
            }
            int col = (nt << 4) + (lane & 15);
            float bi = (col < C) ? b_ih[g * C + col] : 0.f;
            float bh = (col < C) ? b_hh[g * C + col] : 0.f;
            if (g == 0) {
#pragma unroll
                for (int e = 0; e < 4; ++e) r_[nt][e] = sigmoidf_((accI[e] + bi) + (accH[e] + bh));
            } else if (g == 1) {
#pragma unroll
                for (int e = 0; e < 4; ++e) z_[nt][e] = sigmoidf_((accI[e] + bi) + (accH[e] + bh));
            } else {
#pragma unroll
                for (int e = 0; e < 4; ++e) {
                    int row = base + ((lane >> 4) << 2) + e;
                    if (col < C) {
                        float hv = (float)hin[(size_t)row * PH + col];
                        float nn = tanhf_((accI[e] + bi) + r_[nt][e] * (accH[e] + bh));
                        float z = z_[nt][e];
                        hout[(size_t)row * PH + col] = (_Float16)((1.f - z) * nn + z * hv);
                    } else {
                        hout[(size_t)row * PH + col] = (_Float16)0.f;
                    }
                }
            }
        }
    }
}

__global__ __launch_bounds__(256) void gemm_out(const _Float16* __restrict__ h,
                                                const _Float16* __restrict__ wb,
                                                const float* __restrict__ lin_b,
                                                float* __restrict__ out) {
    int wid = threadIdx.x >> 6, lane = threadIdx.x & 63;
    int tile = blockIdx.x * 4 + wid;
    if (tile >= NTILES) return;
    int base = tile * 16;
    int arow = base + (lane & 15);
    half8 a0 = load_a16(h, arow, 0, lane);
    half8 a1 = load_a16(h, arow, 1, lane);
    const _Float16 zz = (_Float16)0.f;
#pragma unroll
    for (int j = 0; j < 8; ++j) {
        a0[j] = a0[j] > zz ? a0[j] : zz;
        a1[j] = a1[j] > zz ? a1[j] : zz;
    }
#pragma unroll
    for (int nt = 0; nt < 4; ++nt) {
        floatx4 acc = {0.f, 0.f, 0.f, 0.f};
        acc = __builtin_amdgcn_mfma_f32_16x16x32_f16(a0, load_b_frag(wb, nt, 0, lane), acc, 0, 0, 0);
        acc = __builtin_amdgcn_mfma_f32_16x16x32_f16(a1, load_b_frag(wb, nt, 1, lane), acc, 0, 0, 0);
        int col = (nt << 4) + (lane & 15);
        if (col < C) {
            float b = lin_b[col];
#pragma unroll
            for (int e = 0; e < 4; ++e) {
                int row = base + ((lane >> 4) << 2) + e;
                out[(size_t)row * C + col] = acc[e] + b;
            }
        }
    }
}

// ---------------- gather: fp16 m rows in, fp16 agg rows out ----------------
// FIX (R17 bug): q==7 lane writes zeros to agg cols 56..63 so every byte of the
// stride-64 agg row is defined — gemm_gru's aA[1] fragment reads k=56..63, which
// otherwise held stale pairs bytes (arbitrary patterns incl. fp16 NaN/Inf).
__global__ __launch_bounds__(256) void gather_kernel(const __half* __restrict__ m_h,
                                                     const int* __restrict__ rowptr,
                                                     const int* __restrict__ col,
                                                     _Float16* __restrict__ agg) {
    int w = (blockIdx.x * 256 + threadIdx.x) >> 6;
    int lane = threadIdx.x & 63;
    if (w >= N_NODES) return;
    int start = rowptr[w], end = rowptr[w + 1];
    int j = lane >> 3, q = lane & 7;
    bool qok = (q < 7);
    int hoff = qok ? (q * 8) : 48;
    float acc0 = 0.f, acc1 = 0.f, acc2 = 0.f, acc3 = 0.f;
    float acc4 = 0.f, acc5 = 0.f, acc6 = 0.f, acc7 = 0.f;

    for (int base = start; base < end; base += 64) {
        int cidx = base + lane;
        int cols = col[cidx < N_EDGES ? cidx : (N_EDGES - 1)];
        int cnt = end - base; if (cnt > 64) cnt = 64;
        int nt8 = (cnt + 7) >> 3;
#pragma unroll 4
        for (int t = 0; t < nt8; ++t) {
            int rel = 8 * t + j;
            int s = __shfl(cols, rel);
            bool valid = qok && (rel < cnt);
            const uint4 v = *reinterpret_cast<const uint4*>(m_h + (size_t)s * PH + hoff);
            float2 f0 = __half22float2(*reinterpret_cast<const __half2*>(&v.x));
            float2 f1 = __half22float2(*reinterpret_cast<const __half2*>(&v.y));
            float2 f2 = __half22float2(*reinterpret_cast<const __half2*>(&v.z));
            float2 f3 = __half22float2(*reinterpret_cast<const __half2*>(&v.w));
            acc0 += valid ? f0.x : 0.f;  acc1 += valid ? f0.y : 0.f;
            acc2 += valid ? f1.x : 0.f;  acc3 += valid ? f1.y : 0.f;
            acc4 += valid ? f2.x : 0.f;  acc5 += valid ? f2.y : 0.f;
            acc6 += valid ? f3.x : 0.f;  acc7 += valid ? f3.y : 0.f;
        }
    }
#pragma unroll
    for (int s = 8; s <= 32; s <<= 1) {
        acc0 += __shfl_xor(acc0, s); acc1 += __shfl_xor(acc1, s);
        acc2 += __shfl_xor(acc2, s); acc3 += __shfl_xor(acc3, s);
        acc4 += __shfl_xor(acc4, s); acc5 += __shfl_xor(acc5, s);
        acc6 += __shfl_xor(acc6, s); acc7 += __shfl_xor(acc7, s);
    }
    if (j == 0) {
        if (qok) {
            half8 o;
            o[0] = (_Float16)acc0; o[1] = (_Float16)acc1;
            o[2] = (_Float16)acc2; o[3] = (_Float16)acc3;
            o[4] = (_Float16)acc4; o[5] = (_Float16)acc5;
            o[6] = (_Float16)acc6; o[7] = (_Float16)acc7;
            *reinterpret_cast<half8*>(agg + (size_t)w * PH + q * 8) = o;
        } else {
            half8 z = {};
            *reinterpret_cast<half8*>(agg + (size_t)w * PH + 56) = z;
        }
    }
}

extern "C" void kernel_launch(void* const* d_in, const int* in_sizes, int n_in,
                              void* d_out, int out_size, void* d_ws, size_t ws_size,
                              hipStream_t stream) {
    const float* x      = (const float*)d_in[0];
    const int*   ei     = (const int*)  d_in[1];
    const float* conv_w = (const float*)d_in[3];
    const float* w_ih   = (const float*)d_in[4];
    const float* w_hh   = (const float*)d_in[5];
    const float* b_ih   = (const float*)d_in[6];
    const float* b_hh   = (const float*)d_in[7];
    const float* lin_w  = (const float*)d_in[9];
    const float* lin_b  = (const float*)d_in[10];
    float* out = (float*)d_out;

    // layout (all fp16 rows stride 64): h0 | h1 | agg | m_h | wb | col | rowptr | cnt | off
    // pairs (14.4 MB) aliases agg (12.8 MB) + head of m_h — both dead until after fill
    _Float16* h0  = (_Float16*)d_ws;
    _Float16* h1  = h0 + NH;
    _Float16* agg = h1 + NH;
    _Float16* m_h = agg + NH;
    _Float16* wb  = m_h + NH;
    unsigned int* pairs = (unsigned int*)agg;
    int* col       = (int*)(wb + 10 * 4096);
    int* rowptr    = col + N_EDGES;             // N_NODES+1
    int* cnt       = rowptr + N_NODES + 1;      // NBUK
    int* bucketOff = cnt + NBUK;                // NBUK+1

    const int initBlocks = (NH + 255) / 256;    // covers h0, wb, cnt
    const int waveBlocks = (N_NODES * 64 + 255) / 256;
    const int gemmBlocks = (NTILES + 3) / 4;

    // fused setup (pad x, weight prep, cnt zero)
    init_kernel<<<initBlocks, 256, 0, stream>>>(x, conv_w, w_ih, w_hh, lin_w, h0, wb, cnt);

    // bucket-sorted CSR build
    partition_kernel<<<EB, 256, 0, stream>>>(ei, cnt, pairs);
    bscan_kernel<<<1, 1024, 0, stream>>>(cnt, bucketOff);
    bucket_fill_kernel<<<NBUK, 256, 0, stream>>>(pairs, cnt, bucketOff, rowptr, col);

    // 3 layers
    gemm_conv<<<gemmBlocks, 256, 0, stream>>>(h0, wb + 0 * 4096, m_h);
    gather_kernel<<<waveBlocks, 256, 0, stream>>>((const __half*)m_h, rowptr, col, agg);
    gemm_gru<<<gemmBlocks, 256, 0, stream>>>(agg, h0, wb + 3 * 4096, wb + 6 * 4096, b_ih, b_hh, h1);

    gemm_conv<<<gemmBlocks, 256, 0, stream>>>(h1, wb + 1 * 4096, m_h);
    gather_kernel<<<waveBlocks, 256, 0, stream>>>((const __half*)m_h, rowptr, col, agg);
    gemm_gru<<<gemmBlocks, 256, 0, stream>>>(agg, h1, wb + 3 * 4096, wb + 6 * 4096, b_ih, b_hh, h0);

    gemm_conv<<<gemmBlocks, 256, 0, stream>>>(h0, wb + 2 * 4096, m_h);
    gather_kernel<<<waveBlocks, 256, 0, stream>>>((const __half*)m_h, rowptr, col, agg);
    gemm_gru<<<gemmBlocks, 256, 0, stream>>>(agg, h0, wb + 3 * 4096, wb + 6 * 4096, b_ih, b_hh, h1);

    gemm_out<<<gemmBlocks, 256, 0, stream>>>(h1, wb + 9 * 4096, lin_b, out);
}

// Round 19
// 445.757 us; speedup vs baseline: 4.3529x; 1.0305x over previous
//
#include <hip/hip_runtime.h>
#include <hip/hip_fp16.h>

#define N_NODES 100000
#define N_EDGES 3200000
#define C 50
#define PH 64          // fp16 row stride for h/agg/m (128 B)
#define NH (N_NODES * PH)
#define NTILES (N_NODES / 16)                 // 6250
#define NB2 391                               // 256-node buckets
#define BSH2 8
#define BMSK2 255
#define BCAP2 9216                            // mean 8184 + ~11 sigma
#define EPB 4096                              // edges per block (partition)
#define EB  ((N_EDGES + EPB - 1) / EPB)       // 782
#define EPT (EPB / 256)                       // 16 edges per thread

typedef _Float16 half8 __attribute__((ext_vector_type(8)));
typedef float floatx4 __attribute__((ext_vector_type(4)));

// ---------------- bucket-sorted CSR build (256-node buckets) ----------------

// partition edges into PADDED bucket segments; cnt[b] = exact bucket size.
// packed pair: p = (src << 8) | (dst & 255)   (src < 2^17 -> 25 bits)
__global__ __launch_bounds__(256) void partition_kernel(const int* __restrict__ ei,
                                                        int* __restrict__ cnt,
                                                        unsigned int* __restrict__ pairs) {
    __shared__ int hist[NB2];
    __shared__ int base[NB2];
    int e0 = blockIdx.x * EPB;
    int b[EPT]; unsigned int p[EPT];
#pragma unroll
    for (int i = 0; i < EPT; ++i) {
        int e = e0 + i * 256 + threadIdx.x;
        bool ok = e < N_EDGES;
        int d = ok ? ei[N_EDGES + e] : 0;
        int s = ok ? ei[e] : 0;
        b[i] = ok ? (d >> BSH2) : -1;
        p[i] = ((unsigned)s << BSH2) | (unsigned)(d & BMSK2);
    }
    for (int t = threadIdx.x; t < NB2; t += 256) hist[t] = 0;
    __syncthreads();
#pragma unroll
    for (int i = 0; i < EPT; ++i)
        if (b[i] >= 0) atomicAdd(&hist[b[i]], 1);
    __syncthreads();
    for (int t = threadIdx.x; t < NB2; t += 256)
        base[t] = hist[t] ? (t * BCAP2 + atomicAdd(&cnt[t], hist[t])) : 0;
    __syncthreads();
    for (int t = threadIdx.x; t < NB2; t += 256) hist[t] = 0;
    __syncthreads();
#pragma unroll
    for (int i = 0; i < EPT; ++i) {
        if (b[i] >= 0) {
            int r = atomicAdd(&hist[b[i]], 1);
            pairs[base[b[i]] + r] = p[i];
        }
    }
}

// exclusive scan of cnt (391) -> bucketOff[0..NB2]
__global__ __launch_bounds__(1024) void bscan_kernel(const int* __restrict__ cnt,
                                                     int* __restrict__ bucketOff) {
    __shared__ int buf[1024];
    int t = threadIdx.x;
    int v = (t < NB2) ? cnt[t] : 0;
    buf[t] = v;
    __syncthreads();
    for (int off = 1; off < 1024; off <<= 1) {
        int tv = (t >= off) ? buf[t - off] : 0;
        __syncthreads();
        buf[t] += tv;
        __syncthreads();
    }
    if (t < NB2) {
        int excl = buf[t] - v;
        bucketOff[t] = excl;
        if (t == NB2 - 1) bucketOff[NB2] = excl + v;
    }
}

// per-bucket local CSR fill (256 nodes/bucket; parallel Hillis-Steele scan)
__global__ __launch_bounds__(256) void bucket_fill_kernel(const unsigned int* __restrict__ pairs,
                                                          const int* __restrict__ cnt,
                                                          const int* __restrict__ bucketOff,
                                                          int* __restrict__ rowptr,
                                                          int* __restrict__ col) {
    __shared__ int deg[256];
    __shared__ int cur[256];
    int b = blockIdx.x;
    int nbase = b << BSH2;
    int n_e = cnt[b];
    int slot0 = b * BCAP2;
    int segB = bucketOff[b];
    int tid = threadIdx.x;
    deg[tid] = 0;
    __syncthreads();
    for (int e = tid; e < n_e; e += 256)
        atomicAdd(&deg[pairs[slot0 + e] & BMSK2], 1);
    __syncthreads();
    int v = deg[tid];
    cur[tid] = v;
    __syncthreads();
    for (int off = 1; off < 256; off <<= 1) {
        int t = (tid >= off) ? cur[tid - off] : 0;
        __syncthreads();
        cur[tid] += t;
        __syncthreads();
    }
    int excl = cur[tid] - v;
    int n = nbase + tid;
    if (n < N_NODES) rowptr[n] = segB + excl;
    __syncthreads();
    cur[tid] = excl;
    __syncthreads();
    for (int e = tid; e < n_e; e += 256) {
        unsigned int p = pairs[slot0 + e];
        int r = atomicAdd(&cur[p & BMSK2], 1);
        col[segB + r] = (int)(p >> BSH2);
    }
    if (b == 0 && tid == 0) rowptr[N_NODES] = N_EDGES;
}

// ---------------- fused setup: pad x -> h0 (fp16), weight prep, cnt zero ----------------
__global__ __launch_bounds__(256) void init_kernel(const float* __restrict__ x,
                                                   const float* __restrict__ conv_w,
                                                   const float* __restrict__ w_ih,
                                                   const float* __restrict__ w_hh,
                                                   const float* __restrict__ lin_w,
                                                   _Float16* __restrict__ h0,
                                                   _Float16* __restrict__ wb,
                                                   int* __restrict__ cnt) {
    int t = blockIdx.x * 256 + threadIdx.x;
    if (t < NH) {
        int n = t >> 6, c = t & 63;
        h0[t] = (c < C) ? (_Float16)x[n * C + c] : (_Float16)0.f;
    }
    if (t < 10 * 4096) {
        int mat = t >> 12, idx = t & 4095, n = idx >> 6, k = idx & 63;
        float v = 0.f;
        if (n < C && k < C) {
            if (mat < 3)      v = conv_w[mat * C * C + k * C + n];
            else if (mat < 6) v = w_ih[((mat - 3) * C + n) * C + k];
            else if (mat < 9) v = w_hh[((mat - 6) * C + n) * C + k];
            else              v = lin_w[n * C + k];
        }
        wb[t] = (_Float16)v;
    }
    if (t < NB2) cnt[t] = 0;
}

// ---------------- MFMA helpers (fp16 [*][64] rows) ----------------
__device__ inline half8 load_a16(const _Float16* __restrict__ base, int row, int ks, int lane) {
    return *(const half8*)(base + (size_t)row * PH + (ks << 5) + ((lane >> 4) << 3));
}

__device__ inline half8 load_b_frag(const _Float16* __restrict__ wb, int nt, int ks, int lane) {
    const _Float16* p = wb + (((nt << 4) + (lane & 15)) << 6) + (ks << 5) + ((lane >> 4) << 3);
    return *(const half8*)p;
}

__device__ inline float sigmoidf_(float x) { return 1.f / (1.f + __expf(-x)); }
__device__ inline float tanhf_(float x)    { return 2.f * sigmoidf_(2.f * x) - 1.f; }

// ---------------- dense kernels via MFMA ----------------
__global__ __launch_bounds__(256) void gemm_conv(const _Float16* __restrict__ h,
                                                 const _Float16* __restrict__ wb,
                                                 _Float16* __restrict__ m_h) {
    int wid = threadIdx.x >> 6, lane = threadIdx.x & 63;
    int tile = blockIdx.x * 4 + wid;
    if (tile >= NTILES) return;
    int base = tile * 16;
    int arow = base + (lane & 15);
    half8 a0 = load_a16(h, arow, 0, lane);
    half8 a1 = load_a16(h, arow, 1, lane);
#pragma unroll
    for (int nt = 0; nt < 4; ++nt) {
        floatx4 acc = {0.f, 0.f, 0.f, 0.f};
        acc = __builtin_amdgcn_mfma_f32_16x16x32_f16(a0, load_b_frag(wb, nt, 0, lane), acc, 0, 0, 0);
        acc = __builtin_amdgcn_mfma_f32_16x16x32_f16(a1, load_b_frag(wb, nt, 1, lane), acc, 0, 0, 0);
        int col = (nt << 4) + (lane & 15);
#pragma unroll
        for (int e = 0; e < 4; ++e) {
            int row = base + ((lane >> 4) << 2) + e;
            m_h[(size_t)row * PH + col] = (_Float16)acc[e];
        }
    }
}

// fused GRU (+ write hout) + conv of NEXT layer via wave-local LDS transpose.
// C-layout (col=lane&15, row=(lane>>4)*4+e) -> LDS tile -> A-layout (row=lane&15,
// k=(lane>>4)*8+j). LDS row padded to 72 halves (144 B) -> 2-way bank alias (free).
__global__ __launch_bounds__(256) void gemm_gru_conv(const _Float16* __restrict__ agg,
                                                     const _Float16* __restrict__ hin,
                                                     const _Float16* __restrict__ wb_ih,
                                                     const _Float16* __restrict__ wb_hh,
                                                     const float* __restrict__ b_ih,
                                                     const float* __restrict__ b_hh,
                                                     const _Float16* __restrict__ wb_conv,
                                                     _Float16* __restrict__ hout,
                                                     _Float16* __restrict__ m_h) {
    __shared__ __align__(16) _Float16 hlds[4][16][72];
    int wid = threadIdx.x >> 6, lane = threadIdx.x & 63;
    int tile = blockIdx.x * 4 + wid;
    bool act = tile < NTILES;
    int base = tile * 16;
    if (act) {
        int arow = base + (lane & 15);
        half8 aA[2], aH[2];
#pragma unroll
        for (int ks = 0; ks < 2; ++ks) {
            aA[ks] = load_a16(agg, arow, ks, lane);
            aH[ks] = load_a16(hin, arow, ks, lane);
        }
        float r_[4][4], z_[4][4];
#pragma unroll
        for (int g = 0; g < 3; ++g) {
            const _Float16* wih = wb_ih + g * 4096;
            const _Float16* whh = wb_hh + g * 4096;
#pragma unroll
            for (int nt = 0; nt < 4; ++nt) {
                floatx4 accI = {0.f, 0.f, 0.f, 0.f};
                floatx4 accH = {0.f, 0.f, 0.f, 0.f};
#pragma unroll
                for (int ks = 0; ks < 2; ++ks) {
                    accI = __builtin_amdgcn_mfma_f32_16x16x32_f16(aA[ks], load_b_frag(wih, nt, ks, lane), accI, 0, 0, 0);
                    accH = __builtin_amdgcn_mfma_f32_16x16x32_f16(aH[ks], load_b_frag(whh, nt, ks, lane), accH, 0, 0, 0);
                }
                int colc = (nt << 4) + (lane & 15);
                float bi = (colc < C) ? b_ih[g * C + colc] : 0.f;
                float bh = (colc < C) ? b_hh[g * C + colc] : 0.f;
                if (g == 0) {
#pragma unroll
                    for (int e = 0; e < 4; ++e) r_[nt][e] = sigmoidf_((accI[e] + bi) + (accH[e] + bh));
                } else if (g == 1) {
#pragma unroll
                    for (int e = 0; e < 4; ++e) z_[nt][e] = sigmoidf_((accI[e] + bi) + (accH[e] + bh));
                } else {
#pragma unroll
                    for (int e = 0; e < 4; ++e) {
                        int rl = ((lane >> 4) << 2) + e;
                        int row = base + rl;
                        _Float16 val = (_Float16)0.f;
                        if (colc < C) {
                            float hv = (float)hin[(size_t)row * PH + colc];
                            float nn = tanhf_((accI[e] + bi) + r_[nt][e] * (accH[e] + bh));
                            float z = z_[nt][e];
                            val = (_Float16)((1.f - z) * nn + z * hv);
                        }
                        hout[(size_t)row * PH + colc] = val;
                        hlds[wid][rl][colc] = val;
                    }
                }
            }
        }
    }
    __syncthreads();
    if (act) {
        half8 a0 = *(const half8*)&hlds[wid][lane & 15][(lane >> 4) << 3];
        half8 a1 = *(const half8*)&hlds[wid][lane & 15][32 + ((lane >> 4) << 3)];
#pragma unroll
        for (int nt = 0; nt < 4; ++nt) {
            floatx4 acc = {0.f, 0.f, 0.f, 0.f};
            acc = __builtin_amdgcn_mfma_f32_16x16x32_f16(a0, load_b_frag(wb_conv, nt, 0, lane), acc, 0, 0, 0);
            acc = __builtin_amdgcn_mfma_f32_16x16x32_f16(a1, load_b_frag(wb_conv, nt, 1, lane), acc, 0, 0, 0);
            int col = (nt << 4) + (lane & 15);
#pragma unroll
            for (int e = 0; e < 4; ++e) {
                int row = base + ((lane >> 4) << 2) + e;
                m_h[(size_t)row * PH + col] = (_Float16)acc[e];
            }
        }
    }
}

// fused GRU (no h write) + relu + output linear; writes fp32 out directly.
__global__ __launch_bounds__(256) void gemm_gru_out(const _Float16* __restrict__ agg,
                                                    const _Float16* __restrict__ hin,
                                                    const _Float16* __restrict__ wb_ih,
                                                    const _Float16* __restrict__ wb_hh,
                                                    const float* __restrict__ b_ih,
                                                    const float* __restrict__ b_hh,
                                                    const _Float16* __restrict__ wb_out,
                                                    const float* __restrict__ lin_b,
                                                    float* __restrict__ out) {
    __shared__ __align__(16) _Float16 hlds[4][16][72];
    int wid = threadIdx.x >> 6, lane = threadIdx.x & 63;
    int tile = blockIdx.x * 4 + wid;
    bool act = tile < NTILES;
    int base = tile * 16;
    if (act) {
        int arow = base + (lane & 15);
        half8 aA[2], aH[2];
#pragma unroll
        for (int ks = 0; ks < 2; ++ks) {
            aA[ks] = load_a16(agg, arow, ks, lane);
            aH[ks] = load_a16(hin, arow, ks, lane);
        }
        float r_[4][4], z_[4][4];
#pragma unroll
        for (int g = 0; g < 3; ++g) {
            const _Float16* wih = wb_ih + g * 4096;
            const _Float16* whh = wb_hh + g * 4096;
#pragma unroll
            for (int nt = 0; nt < 4; ++nt) {
                floatx4 accI = {0.f, 0.f, 0.f, 0.f};
                floatx4 accH = {0.f, 0.f, 0.f, 0.f};
#pragma unroll
                for (int ks = 0; ks < 2; ++ks) {
                    accI = __builtin_amdgcn_mfma_f32_16x16x32_f16(aA[ks], load_b_frag(wih, nt, ks, lane), accI, 0, 0, 0);
                    accH = __builtin_amdgcn_mfma_f32_16x16x32_f16(aH[ks], load_b_frag(whh, nt, ks, lane), accH, 0, 0, 0);
                }
                int colc = (nt << 4) + (lane & 15);
                float bi = (colc < C) ? b_ih[g * C + colc] : 0.f;
                float bh = (colc < C) ? b_hh[g * C + colc] : 0.f;
                if (g == 0) {
#pragma unroll
                    for (int e = 0; e < 4; ++e) r_[nt][e] = sigmoidf_((accI[e] + bi) + (accH[e] + bh));
                } else if (g == 1) {
#pragma unroll
                    for (int e = 0; e < 4; ++e) z_[nt][e] = sigmoidf_((accI[e] + bi) + (accH[e] + bh));
                } else {
#pragma unroll
                    for (int e = 0; e < 4; ++e) {
                        int rl = ((lane >> 4) << 2) + e;
                        int row = base + rl;
                        _Float16 val = (_Float16)0.f;
                        if (colc < C) {
                            float hv = (float)hin[(size_t)row * PH + colc];
                            float nn = tanhf_((accI[e] + bi) + r_[nt][e] * (accH[e] + bh));
                            float z = z_[nt][e];
                            float h3 = (1.f - z) * nn + z * hv;
                            val = (_Float16)(h3 > 0.f ? h3 : 0.f);   // relu fused
                        }
                        hlds[wid][rl][colc] = val;
                    }
                }
            }
        }
    }
    __syncthreads();
    if (act) {
        half8 a0 = *(const half8*)&hlds[wid][lane & 15][(lane >> 4) << 3];
        half8 a1 = *(const half8*)&hlds[wid][lane & 15][32 + ((lane >> 4) << 3)];
#pragma unroll
        for (int nt = 0; nt < 4; ++nt) {
            floatx4 acc = {0.f, 0.f, 0.f, 0.f};
            acc = __builtin_amdgcn_mfma_f32_16x16x32_f16(a0, load_b_frag(wb_out, nt, 0, lane), acc, 0, 0, 0);
            acc = __builtin_amdgcn_mfma_f32_16x16x32_f16(a1, load_b_frag(wb_out, nt, 1, lane), acc, 0, 0, 0);
            int col = (nt << 4) + (lane & 15);
            if (col < C) {
                float b = lin_b[col];
#pragma unroll
                for (int e = 0; e < 4; ++e) {
                    int row = base + ((lane >> 4) << 2) + e;
                    out[(size_t)row * C + col] = acc[e] + b;
                }
            }
        }
    }
}

// ---------------- gather: fp16 m rows in, fp16 agg rows out ----------------
// q==7 lane zeroes agg cols 56..63 (stride-64 rows fully defined — R17 lesson).
__global__ __launch_bounds__(256) void gather_kernel(const __half* __restrict__ m_h,
                                                     const int* __restrict__ rowptr,
                                                     const int* __restrict__ col,
                                                     _Float16* __restrict__ agg) {
    int w = (blockIdx.x * 256 + threadIdx.x) >> 6;
    int lane = threadIdx.x & 63;
    if (w >= N_NODES) return;
    int start = rowptr[w], end = rowptr[w + 1];
    int j = lane >> 3, q = lane & 7;
    bool qok = (q < 7);
    int hoff = qok ? (q * 8) : 48;
    float acc0 = 0.f, acc1 = 0.f, acc2 = 0.f, acc3 = 0.f;
    float acc4 = 0.f, acc5 = 0.f, acc6 = 0.f, acc7 = 0.f;

    for (int base = start; base < end; base += 64) {
        int cidx = base + lane;
        int cols = col[cidx < N_EDGES ? cidx : (N_EDGES - 1)];
        int cnt = end - base; if (cnt > 64) cnt = 64;
        int nt8 = (cnt + 7) >> 3;
#pragma unroll 4
        for (int t = 0; t < nt8; ++t) {
            int rel = 8 * t + j;
            int s = __shfl(cols, rel);
            bool valid = qok && (rel < cnt);
            const uint4 v = *reinterpret_cast<const uint4*>(m_h + (size_t)s * PH + hoff);
            float2 f0 = __half22float2(*reinterpret_cast<const __half2*>(&v.x));
            float2 f1 = __half22float2(*reinterpret_cast<const __half2*>(&v.y));
            float2 f2 = __half22float2(*reinterpret_cast<const __half2*>(&v.z));
            float2 f3 = __half22float2(*reinterpret_cast<const __half2*>(&v.w));
            acc0 += valid ? f0.x : 0.f;  acc1 += valid ? f0.y : 0.f;
            acc2 += valid ? f1.x : 0.f;  acc3 += valid ? f1.y : 0.f;
            acc4 += valid ? f2.x : 0.f;  acc5 += valid ? f2.y : 0.f;
            acc6 += valid ? f3.x : 0.f;  acc7 += valid ? f3.y : 0.f;
        }
    }
#pragma unroll
    for (int s = 8; s <= 32; s <<= 1) {
        acc0 += __shfl_xor(acc0, s); acc1 += __shfl_xor(acc1, s);
        acc2 += __shfl_xor(acc2, s); acc3 += __shfl_xor(acc3, s);
        acc4 += __shfl_xor(acc4, s); acc5 += __shfl_xor(acc5, s);
        acc6 += __shfl_xor(acc6, s); acc7 += __shfl_xor(acc7, s);
    }
    if (j == 0) {
        if (qok) {
            half8 o;
            o[0] = (_Float16)acc0; o[1] = (_Float16)acc1;
            o[2] = (_Float16)acc2; o[3] = (_Float16)acc3;
            o[4] = (_Float16)acc4; o[5] = (_Float16)acc5;
            o[6] = (_Float16)acc6; o[7] = (_Float16)acc7;
            *reinterpret_cast<half8*>(agg + (size_t)w * PH + q * 8) = o;
        } else {
            half8 z = {};
            *reinterpret_cast<half8*>(agg + (size_t)w * PH + 56) = z;
        }
    }
}

extern "C" void kernel_launch(void* const* d_in, const int* in_sizes, int n_in,
                              void* d_out, int out_size, void* d_ws, size_t ws_size,
                              hipStream_t stream) {
    const float* x      = (const float*)d_in[0];
    const int*   ei     = (const int*)  d_in[1];
    const float* conv_w = (const float*)d_in[3];
    const float* w_ih   = (const float*)d_in[4];
    const float* w_hh   = (const float*)d_in[5];
    const float* b_ih   = (const float*)d_in[6];
    const float* b_hh   = (const float*)d_in[7];
    const float* lin_w  = (const float*)d_in[9];
    const float* lin_b  = (const float*)d_in[10];
    float* out = (float*)d_out;

    // layout (fp16 rows stride 64): h0 | h1 | agg | m_h | wb | col | rowptr | cnt | off
    // pairs (391*9216*4 = 14.4 MB) aliases agg (12.8 MB) + head of m_h — dead after fill
    _Float16* h0  = (_Float16*)d_ws;
    _Float16* h1  = h0 + NH;
    _Float16* agg = h1 + NH;
    _Float16* m_h = agg + NH;
    _Float16* wb  = m_h + NH;
    unsigned int* pairs = (unsigned int*)agg;
    int* col       = (int*)(wb + 10 * 4096);
    int* rowptr    = col + N_EDGES;             // N_NODES+1
    int* cnt       = rowptr + N_NODES + 1;      // NB2
    int* bucketOff = cnt + NB2;                 // NB2+1

    const int initBlocks = (NH + 255) / 256;
    const int waveBlocks = (N_NODES * 64 + 255) / 256;
    const int gemmBlocks = (NTILES + 3) / 4;

    // fused setup
    init_kernel<<<initBlocks, 256, 0, stream>>>(x, conv_w, w_ih, w_hh, lin_w, h0, wb, cnt);

    // bucket-sorted CSR build
    partition_kernel<<<EB, 256, 0, stream>>>(ei, cnt, pairs);
    bscan_kernel<<<1, 1024, 0, stream>>>(cnt, bucketOff);
    bucket_fill_kernel<<<NB2, 256, 0, stream>>>(pairs, cnt, bucketOff, rowptr, col);

    // layer 1
    gemm_conv<<<gemmBlocks, 256, 0, stream>>>(h0, wb + 0 * 4096, m_h);
    gather_kernel<<<waveBlocks, 256, 0, stream>>>((const __half*)m_h, rowptr, col, agg);
    // layer 1 GRU fused with layer-2 conv
    gemm_gru_conv<<<gemmBlocks, 256, 0, stream>>>(agg, h0, wb + 3 * 4096, wb + 6 * 4096,
                                                  b_ih, b_hh, wb + 1 * 4096, h1, m_h);
    gather_kernel<<<waveBlocks, 256, 0, stream>>>((const __half*)m_h, rowptr, col, agg);
    // layer 2 GRU fused with layer-3 conv
    gemm_gru_conv<<<gemmBlocks, 256, 0, stream>>>(agg, h1, wb + 3 * 4096, wb + 6 * 4096,
                                                  b_ih, b_hh, wb + 2 * 4096, h0, m_h);
    gather_kernel<<<waveBlocks, 256, 0, stream>>>((const __half*)m_h, rowptr, col, agg);
    // layer 3 GRU fused with relu + output linear (h3 never materialized)
    gemm_gru_out<<<gemmBlocks, 256, 0, stream>>>(agg, h0, wb + 3 * 4096, wb + 6 * 4096,
                                                 b_ih, b_hh, wb + 9 * 4096, lin_b, out);
}